// Round 4
// baseline (243.577 us; speedup 1.0000x reference)
//
#include <hip/hip_runtime.h>
#include <math.h>

#define SLOPE 0.01f

using bf16x8 = __attribute__((ext_vector_type(8))) short;
using f32x4  = __attribute__((ext_vector_type(4))) float;

__device__ __forceinline__ unsigned short f2bf(float f) {
  unsigned int u = __float_as_uint(f);
  unsigned int r = 0x7FFFu + ((u >> 16) & 1u);
  return (unsigned short)((u + r) >> 16);
}
__device__ __forceinline__ float bflo(unsigned int v) {  // low ushort -> float
  return __uint_as_float(v << 16);
}
__device__ __forceinline__ float bfhi(unsigned int v) {  // high ushort -> float
  return __uint_as_float(v & 0xFFFF0000u);
}

// ---------------------------------------------------------------
// prep: fused conv_x | conv_w | crel (2 rel/block) | hist
// ---------------------------------------------------------------
__global__ __launch_bounds__(256) void prep(
    const float* __restrict__ x, unsigned short* __restrict__ xb, int total8, int B0,
    const float* __restrict__ W1, unsigned short* __restrict__ WT, int B1,
    const float* __restrict__ rel, const float* __restrict__ b1,
    const float* __restrict__ w2,
    unsigned short* __restrict__ Crelbf, float* __restrict__ pC, int n_rel, int B2,
    const int* __restrict__ dsts, int* __restrict__ deg, int E) {
  int b = blockIdx.x;
  int tid = threadIdx.x;
  if (b < B0) {
    // x fp32 -> bf16, 8 elems/thread
    int i = b * 256 + tid;
    if (i < total8) {
      const float4* p = (const float4*)(x + (size_t)i * 8);
      float4 v0 = p[0], v1 = p[1];
      union { unsigned short us[8]; uint4 u4; } pk;
      pk.us[0] = f2bf(v0.x); pk.us[1] = f2bf(v0.y);
      pk.us[2] = f2bf(v0.z); pk.us[3] = f2bf(v0.w);
      pk.us[4] = f2bf(v1.x); pk.us[5] = f2bf(v1.y);
      pk.us[6] = f2bf(v1.z); pk.us[7] = f2bf(v1.w);
      *(uint4*)(xb + (size_t)i * 8) = pk.u4;
    }
  } else if (b < B1) {
    // WT[n][k] = bf16(W1[(n>=128?128:0)+k][n&127]), 256x128
    int idx = (b - B0) * 256 + tid;   // exactly 32768 over 128 blocks
    int n = idx >> 7, k = idx & 127;
    int src_row = ((n >> 7) << 7) + k;
    WT[n * 128 + k] = f2bf(W1[src_row * 128 + (n & 127)]);
  } else if (b < B2) {
    // Crel[r] = rel[r] @ W1[256:384,:] + b1 (bf16); pC[r] = Crel[r].w2
    __shared__ float rs[2][128];
    __shared__ float red[2][128];
    int h = tid >> 7, d = tid & 127;
    int r = (b - B1) * 2 + h;
    bool valid = r < n_rel;
    rs[h][d] = valid ? rel[r * 128 + d] : 0.f;
    __syncthreads();
    float acc = b1[d];
    for (int k = 0; k < 128; ++k)
      acc = fmaf(rs[h][k], W1[(256 + k) * 128 + d], acc);
    if (valid) Crelbf[r * 128 + d] = f2bf(acc);
    red[h][d] = acc * w2[d];
    __syncthreads();
    for (int s = 64; s > 0; s >>= 1) {
      if (d < s) red[h][d] += red[h][d + s];
      __syncthreads();
    }
    if (d == 0 && valid) pC[r] = red[h][0];
  } else {
    int i = (b - B2) * 256 + tid;
    if (i < E) atomicAdd(&deg[dsts[i]], 1);
  }
}

// ---------------------------------------------------------------
// Single-pass MFMA GEMM: [A|B] = xb @ WT^T. Block = 64 M x 256 N,
// 4 waves (2m x 2n), wave = 32M x 128N. A,B stored bf16.
// Fused pA/pB = row-dot with w2 via shfl reduce (no LDS).
// ---------------------------------------------------------------
__global__ __launch_bounds__(256) void gemm_mfma(
    const unsigned short* __restrict__ xb, const unsigned short* __restrict__ WT,
    const float* __restrict__ w2,
    unsigned short* __restrict__ Abf, unsigned short* __restrict__ Bmbf,
    float* __restrict__ pA, float* __restrict__ pB, int M) {
  int tid  = threadIdx.x;
  int wave = tid >> 6, lane = tid & 63;
  int wm = wave >> 1, wn = wave & 1;
  int l15 = lane & 15, l4 = lane >> 4;
  int m0 = blockIdx.x * 64;

  f32x4 acc[2][8];
  #pragma unroll
  for (int mi = 0; mi < 2; ++mi)
    #pragma unroll
    for (int ni = 0; ni < 8; ++ni) acc[mi][ni] = (f32x4){0.f, 0.f, 0.f, 0.f};

  int arow0 = m0 + wm * 32 + l15;
  int arow1 = arow0 + 16;
  int ar0 = arow0 < M ? arow0 : M - 1;
  int ar1 = arow1 < M ? arow1 : M - 1;
  const unsigned short* abase0 = xb + (size_t)ar0 * 128 + l4 * 8;
  const unsigned short* abase1 = xb + (size_t)ar1 * 128 + l4 * 8;
  const unsigned short* bbase  = WT + (size_t)(wn * 128 + l15) * 128 + l4 * 8;

  #pragma unroll
  for (int ks = 0; ks < 4; ++ks) {
    bf16x8 af0 = *(const bf16x8*)(abase0 + ks * 32);
    bf16x8 af1 = *(const bf16x8*)(abase1 + ks * 32);
    #pragma unroll
    for (int ni = 0; ni < 8; ++ni) {
      bf16x8 bf = *(const bf16x8*)(bbase + ni * 16 * 128 + ks * 32);
      acc[0][ni] = __builtin_amdgcn_mfma_f32_16x16x32_bf16(af0, bf, acc[0][ni], 0, 0, 0);
      acc[1][ni] = __builtin_amdgcn_mfma_f32_16x16x32_bf16(af1, bf, acc[1][ni], 0, 0, 0);
    }
  }

  // C/D layout: col = ni*16 + l15, row = m0 + wm*32 + mi*16 + l4*4 + r
  unsigned short* dstp = (wn == 0) ? Abf : Bmbf;
  #pragma unroll
  for (int mi = 0; mi < 2; ++mi) {
    #pragma unroll
    for (int ni = 0; ni < 8; ++ni) {
      int coll = ni * 16 + l15;
      #pragma unroll
      for (int r = 0; r < 4; ++r) {
        int row = m0 + wm * 32 + mi * 16 + l4 * 4 + r;
        if (row < M) dstp[(size_t)row * 128 + coll] = f2bf(acc[mi][ni][r]);
      }
    }
  }

  // fused dot with w2 -> pA (wn==0) / pB (wn==1)
  float w2c[8];
  #pragma unroll
  for (int ni = 0; ni < 8; ++ni) w2c[ni] = w2[ni * 16 + l15];
  float* pdst = (wn == 0) ? pA : pB;
  #pragma unroll
  for (int mi = 0; mi < 2; ++mi) {
    #pragma unroll
    for (int r = 0; r < 4; ++r) {
      float v = 0.f;
      #pragma unroll
      for (int ni = 0; ni < 8; ++ni) v = fmaf(acc[mi][ni][r], w2c[ni], v);
      v += __shfl_xor(v, 1, 64);
      v += __shfl_xor(v, 2, 64);
      v += __shfl_xor(v, 4, 64);
      v += __shfl_xor(v, 8, 64);
      if (l15 == 0) {
        int row = m0 + wm * 32 + mi * 16 + l4 * 4 + r;
        if (row < M) pdst[row] = v;
      }
    }
  }
}

// ---------------------------------------------------------------
// Single-block chunked scan: off/pos = exclusive prefix of deg
// ---------------------------------------------------------------
__global__ __launch_bounds__(1024) void scan_all(
    const int* __restrict__ deg, int* __restrict__ off,
    int* __restrict__ pos, int n) {
  __shared__ int tot[1024];
  int t = threadIdx.x;
  int chunk = (n + 1023) >> 10;
  int lo = t * chunk; if (lo > n) lo = n;
  int hi = lo + chunk; if (hi > n) hi = n;
  int s = 0;
  for (int i = lo; i < hi; ++i) s += deg[i];
  int own = s;
  tot[t] = s;
  __syncthreads();
  for (int sft = 1; sft < 1024; sft <<= 1) {
    int add = (t >= sft) ? tot[t - sft] : 0;
    __syncthreads();
    tot[t] += add;
    __syncthreads();
  }
  int run = tot[t] - own;
  for (int i = lo; i < hi; ++i) {
    off[i] = run; pos[i] = run;
    run += deg[i];
  }
}

// ---------------------------------------------------------------
// fill CSR slots: packed (src | type<<16) + precomputed lrelu logit
// ---------------------------------------------------------------
__global__ void fill_perm(
    const int* __restrict__ srcs, const int* __restrict__ dsts,
    const int* __restrict__ types,
    const float* __restrict__ pA, const float* __restrict__ pB,
    const float* __restrict__ pC,
    int* __restrict__ pos,
    unsigned int* __restrict__ stperm, float* __restrict__ bperm, int E) {
  int i = blockIdx.x * 256 + threadIdx.x;
  if (i < E) {
    int dn = dsts[i];
    int s  = srcs[i];
    int t  = types[i];
    float bv = pA[s] + pB[dn] + pC[t];
    bv = bv > 0.f ? bv : SLOPE * bv;
    int p = atomicAdd(&pos[dn], 1);
    stperm[p] = (unsigned int)s | ((unsigned int)t << 16);
    bperm[p] = bv;
  }
}

// ---------------------------------------------------------------
// Per-node softmax + weighted gather. 4 edges in flight.
// out[n] = lrelu( sum_e alpha_e (A[s]+Crel[t]) + B[n] ), all bf16 gathers
// ---------------------------------------------------------------
__global__ __launch_bounds__(256) void aggregate(
    const int* __restrict__ off, const int* __restrict__ deg,
    const unsigned int* __restrict__ stperm, const float* __restrict__ bperm,
    const unsigned short* __restrict__ Abf,
    const unsigned short* __restrict__ Bmbf,
    const unsigned short* __restrict__ Crelbf,
    float* __restrict__ out, int n_nodes) {
  int n = blockIdx.x * 4 + (threadIdx.x >> 6);
  if (n >= n_nodes) return;
  int lane = threadIdx.x & 63;
  int start = off[n];
  int dcnt = deg[n];
  size_t obase = (size_t)n * 128 + 2 * lane;
  if (dcnt == 0) {
    *(float2*)(out + obase) = (float2){0.f, 0.f};
    return;
  }
  float m = -1e30f;
  for (int i = lane; i < dcnt; i += 64) m = fmaxf(m, bperm[start + i]);
  #pragma unroll
  for (int s = 32; s; s >>= 1) m = fmaxf(m, __shfl_xor(m, s, 64));

  float acc0 = 0.f, acc1 = 0.f, S = 0.f;
  int cl2 = 2 * lane;
  int i = 0;
  for (; i + 4 <= dcnt; i += 4) {
    unsigned int st[4]; float bb[4];
    #pragma unroll
    for (int j = 0; j < 4; ++j) {
      st[j] = stperm[start + i + j];
      bb[j] = bperm[start + i + j];
    }
    unsigned int av[4], cv[4];
    #pragma unroll
    for (int j = 0; j < 4; ++j) {
      av[j] = *(const unsigned int*)(Abf + ((size_t)(st[j] & 0xFFFFu) << 7) + cl2);
      cv[j] = *(const unsigned int*)(Crelbf + ((st[j] >> 16) << 7) + cl2);
    }
    #pragma unroll
    for (int j = 0; j < 4; ++j) {
      float ex = __expf(bb[j] - m);
      S += ex;
      acc0 = fmaf(ex, bflo(av[j]) + bflo(cv[j]), acc0);
      acc1 = fmaf(ex, bfhi(av[j]) + bfhi(cv[j]), acc1);
    }
  }
  for (; i < dcnt; ++i) {
    unsigned int st = stperm[start + i];
    float ex = __expf(bperm[start + i] - m);
    unsigned int av = *(const unsigned int*)(Abf + ((size_t)(st & 0xFFFFu) << 7) + cl2);
    unsigned int cv = *(const unsigned int*)(Crelbf + ((st >> 16) << 7) + cl2);
    S += ex;
    acc0 = fmaf(ex, bflo(av) + bflo(cv), acc0);
    acc1 = fmaf(ex, bfhi(av) + bfhi(cv), acc1);
  }
  float inv = 1.f / S;
  unsigned int bm = *(const unsigned int*)(Bmbf + obase);
  float o0 = acc0 * inv + bflo(bm);
  float o1 = acc1 * inv + bfhi(bm);
  o0 = o0 > 0.f ? o0 : SLOPE * o0;
  o1 = o1 > 0.f ? o1 : SLOPE * o1;
  *(float2*)(out + obase) = (float2){o0, o1};
}

extern "C" void kernel_launch(void* const* d_in, const int* in_sizes, int n_in,
                              void* d_out, int out_size, void* d_ws, size_t ws_size,
                              hipStream_t stream) {
  const float* x    = (const float*)d_in[0];
  const float* rel  = (const float*)d_in[1];
  const float* W1   = (const float*)d_in[2];
  const float* b1   = (const float*)d_in[3];
  const float* w2   = (const float*)d_in[4];
  const int* edge_index = (const int*)d_in[5];
  const int* edge_type  = (const int*)d_in[6];

  int n_nodes = in_sizes[0] / 128;
  int n_rel   = in_sizes[1] / 128;
  int E       = in_sizes[6];
  const int* srcs = edge_index;
  const int* dsts = edge_index + E;
  float* out = (float*)d_out;

  auto align256 = [](size_t v) { return (v + 255) & ~(size_t)255; };
  char* ws = (char*)d_ws;
  unsigned short* xb     = (unsigned short*)ws; ws += align256((size_t)n_nodes * 128 * 2);
  unsigned short* WT     = (unsigned short*)ws; ws += align256(256 * 128 * 2);
  unsigned short* Abf    = (unsigned short*)ws; ws += align256((size_t)n_nodes * 128 * 2);
  unsigned short* Bmbf   = (unsigned short*)ws; ws += align256((size_t)n_nodes * 128 * 2);
  unsigned short* Crelbf = (unsigned short*)ws; ws += align256((size_t)n_rel * 128 * 2);
  float* pA    = (float*)ws; ws += align256((size_t)n_nodes * 4);
  float* pB    = (float*)ws; ws += align256((size_t)n_nodes * 4);
  float* pC    = (float*)ws; ws += align256((size_t)n_rel * 4);
  int* deg     = (int*)ws;   ws += align256((size_t)n_nodes * 4);
  int* off     = (int*)ws;   ws += align256((size_t)n_nodes * 4);
  int* pos     = (int*)ws;   ws += align256((size_t)n_nodes * 4);
  unsigned int* stperm = (unsigned int*)ws; ws += align256((size_t)E * 4);
  float* bperm = (float*)ws; ws += align256((size_t)E * 4);

  hipMemsetAsync(deg, 0, (size_t)n_nodes * 4, stream);

  int total8 = n_nodes * 16;
  int B0 = (total8 + 255) / 256;          // conv_x blocks
  int B1 = B0 + 128;                      // conv_w blocks (256*128/256)
  int B2 = B1 + (n_rel + 1) / 2;          // crel blocks (2 rel each)
  int B3 = B2 + (E + 255) / 256;          // hist blocks
  prep<<<B3, 256, 0, stream>>>(x, xb, total8, B0, W1, WT, B1,
                               rel, b1, w2, Crelbf, pC, n_rel, B2,
                               dsts, deg, E);

  gemm_mfma<<<(n_nodes + 63) / 64, 256, 0, stream>>>(
      xb, WT, w2, Abf, Bmbf, pA, pB, n_nodes);

  scan_all<<<1, 1024, 0, stream>>>(deg, off, pos, n_nodes);

  fill_perm<<<(E + 255) / 256, 256, 0, stream>>>(
      srcs, dsts, edge_type, pA, pB, pC, pos, stperm, bperm, E);

  aggregate<<<(n_nodes + 3) / 4, 256, 0, stream>>>(
      off, deg, stperm, bperm, Abf, Bmbf, Crelbf, out, n_nodes);
}

// Round 5
// 149.547 us; speedup vs baseline: 1.6288x; 1.6288x over previous
//
#include <hip/hip_runtime.h>
#include <math.h>

#define SLOPE 0.01f

using bf16x8 = __attribute__((ext_vector_type(8))) short;
using f32x4  = __attribute__((ext_vector_type(4))) float;

__device__ __forceinline__ unsigned short f2bf(float f) {
  unsigned int u = __float_as_uint(f);
  unsigned int r = 0x7FFFu + ((u >> 16) & 1u);
  return (unsigned short)((u + r) >> 16);
}
__device__ __forceinline__ float bflo(unsigned int v) {  // low ushort -> float
  return __uint_as_float(v << 16);
}
__device__ __forceinline__ float bfhi(unsigned int v) {  // high ushort -> float
  return __uint_as_float(v & 0xFFFF0000u);
}

// ---------------------------------------------------------------
// prep: fused conv_x | conv_w | crel (2 rel/block) | hist
// ---------------------------------------------------------------
__global__ __launch_bounds__(256) void prep(
    const float* __restrict__ x, unsigned short* __restrict__ xb, int total8, int B0,
    const float* __restrict__ W1, unsigned short* __restrict__ WT, int B1,
    const float* __restrict__ rel, const float* __restrict__ b1,
    const float* __restrict__ w2,
    unsigned short* __restrict__ Crelbf, float* __restrict__ pC, int n_rel, int B2,
    const int* __restrict__ dsts, int* __restrict__ deg, int E) {
  int b = blockIdx.x;
  int tid = threadIdx.x;
  if (b < B0) {
    // x fp32 -> bf16, 8 elems/thread
    int i = b * 256 + tid;
    if (i < total8) {
      const float4* p = (const float4*)(x + (size_t)i * 8);
      float4 v0 = p[0], v1 = p[1];
      union { unsigned short us[8]; uint4 u4; } pk;
      pk.us[0] = f2bf(v0.x); pk.us[1] = f2bf(v0.y);
      pk.us[2] = f2bf(v0.z); pk.us[3] = f2bf(v0.w);
      pk.us[4] = f2bf(v1.x); pk.us[5] = f2bf(v1.y);
      pk.us[6] = f2bf(v1.z); pk.us[7] = f2bf(v1.w);
      *(uint4*)(xb + (size_t)i * 8) = pk.u4;
    }
  } else if (b < B1) {
    // WT[n][k] = bf16(W1[(n>=128?128:0)+k][n&127]), 256x128
    int idx = (b - B0) * 256 + tid;   // exactly 32768 over 128 blocks
    int n = idx >> 7, k = idx & 127;
    int src_row = ((n >> 7) << 7) + k;
    WT[n * 128 + k] = f2bf(W1[src_row * 128 + (n & 127)]);
  } else if (b < B2) {
    // Crel[r] = rel[r] @ W1[256:384,:] + b1 (bf16); pC[r] = Crel[r].w2
    __shared__ float rs[2][128];
    __shared__ float red[2][128];
    int h = tid >> 7, d = tid & 127;
    int r = (b - B1) * 2 + h;
    bool valid = r < n_rel;
    rs[h][d] = valid ? rel[r * 128 + d] : 0.f;
    __syncthreads();
    float acc = b1[d];
    for (int k = 0; k < 128; ++k)
      acc = fmaf(rs[h][k], W1[(256 + k) * 128 + d], acc);
    if (valid) Crelbf[r * 128 + d] = f2bf(acc);
    red[h][d] = acc * w2[d];
    __syncthreads();
    for (int s = 64; s > 0; s >>= 1) {
      if (d < s) red[h][d] += red[h][d + s];
      __syncthreads();
    }
    if (d == 0 && valid) pC[r] = red[h][0];
  } else {
    int i = (b - B2) * 256 + tid;
    if (i < E) atomicAdd(&deg[dsts[i]], 1);
  }
}

// ---------------------------------------------------------------
// Single-pass MFMA GEMM: [A|B] = xb @ WT^T. Block = 64 M x 256 N,
// 4 waves (2m x 2n), wave = 32M x 128N. A,B stored bf16.
// Fused pA/pB = row-dot with w2 via shfl reduce (no LDS).
// ---------------------------------------------------------------
__global__ __launch_bounds__(256) void gemm_mfma(
    const unsigned short* __restrict__ xb, const unsigned short* __restrict__ WT,
    const float* __restrict__ w2,
    unsigned short* __restrict__ Abf, unsigned short* __restrict__ Bmbf,
    float* __restrict__ pA, float* __restrict__ pB, int M) {
  int tid  = threadIdx.x;
  int wave = tid >> 6, lane = tid & 63;
  int wm = wave >> 1, wn = wave & 1;
  int l15 = lane & 15, l4 = lane >> 4;
  int m0 = blockIdx.x * 64;

  f32x4 acc[2][8];
  #pragma unroll
  for (int mi = 0; mi < 2; ++mi)
    #pragma unroll
    for (int ni = 0; ni < 8; ++ni) acc[mi][ni] = (f32x4){0.f, 0.f, 0.f, 0.f};

  int arow0 = m0 + wm * 32 + l15;
  int arow1 = arow0 + 16;
  int ar0 = arow0 < M ? arow0 : M - 1;
  int ar1 = arow1 < M ? arow1 : M - 1;
  const unsigned short* abase0 = xb + (size_t)ar0 * 128 + l4 * 8;
  const unsigned short* abase1 = xb + (size_t)ar1 * 128 + l4 * 8;
  const unsigned short* bbase  = WT + (size_t)(wn * 128 + l15) * 128 + l4 * 8;

  #pragma unroll
  for (int ks = 0; ks < 4; ++ks) {
    bf16x8 af0 = *(const bf16x8*)(abase0 + ks * 32);
    bf16x8 af1 = *(const bf16x8*)(abase1 + ks * 32);
    #pragma unroll
    for (int ni = 0; ni < 8; ++ni) {
      bf16x8 bf = *(const bf16x8*)(bbase + ni * 16 * 128 + ks * 32);
      acc[0][ni] = __builtin_amdgcn_mfma_f32_16x16x32_bf16(af0, bf, acc[0][ni], 0, 0, 0);
      acc[1][ni] = __builtin_amdgcn_mfma_f32_16x16x32_bf16(af1, bf, acc[1][ni], 0, 0, 0);
    }
  }

  // C/D layout: col = ni*16 + l15, row = m0 + wm*32 + mi*16 + l4*4 + r
  unsigned short* dstp = (wn == 0) ? Abf : Bmbf;
  #pragma unroll
  for (int mi = 0; mi < 2; ++mi) {
    #pragma unroll
    for (int ni = 0; ni < 8; ++ni) {
      int coll = ni * 16 + l15;
      #pragma unroll
      for (int r = 0; r < 4; ++r) {
        int row = m0 + wm * 32 + mi * 16 + l4 * 4 + r;
        if (row < M) dstp[(size_t)row * 128 + coll] = f2bf(acc[mi][ni][r]);
      }
    }
  }

  // fused dot with w2 -> pA (wn==0) / pB (wn==1)
  float w2c[8];
  #pragma unroll
  for (int ni = 0; ni < 8; ++ni) w2c[ni] = w2[ni * 16 + l15];
  float* pdst = (wn == 0) ? pA : pB;
  #pragma unroll
  for (int mi = 0; mi < 2; ++mi) {
    #pragma unroll
    for (int r = 0; r < 4; ++r) {
      float v = 0.f;
      #pragma unroll
      for (int ni = 0; ni < 8; ++ni) v = fmaf(acc[mi][ni][r], w2c[ni], v);
      v += __shfl_xor(v, 1, 64);
      v += __shfl_xor(v, 2, 64);
      v += __shfl_xor(v, 4, 64);
      v += __shfl_xor(v, 8, 64);
      if (l15 == 0) {
        int row = m0 + wm * 32 + mi * 16 + l4 * 4 + r;
        if (row < M) pdst[row] = v;
      }
    }
  }
}

// ---------------------------------------------------------------
// Multi-block 3-stage scan (proven in rounds 2-3)
// ---------------------------------------------------------------
__global__ __launch_bounds__(1024) void scan1(
    const int* __restrict__ deg, int* __restrict__ off,
    int* __restrict__ partial, int n) {
  __shared__ int sdata[1024];
  int t = threadIdx.x;
  int i = blockIdx.x * 1024 + t;
  int v = (i < n) ? deg[i] : 0;
  sdata[t] = v;
  __syncthreads();
  for (int s = 1; s < 1024; s <<= 1) {
    int add = (t >= s) ? sdata[t - s] : 0;
    __syncthreads();
    sdata[t] += add;
    __syncthreads();
  }
  if (i < n) off[i] = sdata[t] - v;
  if (t == 1023) partial[blockIdx.x] = sdata[1023];
}

__global__ __launch_bounds__(1024) void scan2(int* __restrict__ partial, int nb) {
  __shared__ int sdata[1024];
  int t = threadIdx.x;
  int v = (t < nb) ? partial[t] : 0;
  sdata[t] = v;
  __syncthreads();
  for (int s = 1; s < 1024; s <<= 1) {
    int add = (t >= s) ? sdata[t - s] : 0;
    __syncthreads();
    sdata[t] += add;
    __syncthreads();
  }
  if (t < nb) partial[t] = sdata[t] - v;
}

__global__ __launch_bounds__(1024) void scan3(
    int* __restrict__ off, int* __restrict__ pos,
    const int* __restrict__ partial, int n) {
  int i = blockIdx.x * 1024 + threadIdx.x;
  if (i < n) {
    int o = off[i] + partial[blockIdx.x];
    off[i] = o;
    pos[i] = o;
  }
}

// ---------------------------------------------------------------
// fill CSR slots: packed (src | type<<16) + precomputed lrelu logit
// ---------------------------------------------------------------
__global__ void fill_perm(
    const int* __restrict__ srcs, const int* __restrict__ dsts,
    const int* __restrict__ types,
    const float* __restrict__ pA, const float* __restrict__ pB,
    const float* __restrict__ pC,
    int* __restrict__ pos,
    unsigned int* __restrict__ stperm, float* __restrict__ bperm, int E) {
  int i = blockIdx.x * 256 + threadIdx.x;
  if (i < E) {
    int dn = dsts[i];
    int s  = srcs[i];
    int t  = types[i];
    float bv = pA[s] + pB[dn] + pC[t];
    bv = bv > 0.f ? bv : SLOPE * bv;
    int p = atomicAdd(&pos[dn], 1);
    stperm[p] = (unsigned int)s | ((unsigned int)t << 16);
    bperm[p] = bv;
  }
}

// ---------------------------------------------------------------
// Per-node softmax + weighted gather. 4 edges in flight.
// out[n] = lrelu( sum_e alpha_e (A[s]+Crel[t]) + B[n] ), all bf16 gathers
// ---------------------------------------------------------------
__global__ __launch_bounds__(256) void aggregate(
    const int* __restrict__ off, const int* __restrict__ deg,
    const unsigned int* __restrict__ stperm, const float* __restrict__ bperm,
    const unsigned short* __restrict__ Abf,
    const unsigned short* __restrict__ Bmbf,
    const unsigned short* __restrict__ Crelbf,
    float* __restrict__ out, int n_nodes) {
  int n = blockIdx.x * 4 + (threadIdx.x >> 6);
  if (n >= n_nodes) return;
  int lane = threadIdx.x & 63;
  int start = off[n];
  int dcnt = deg[n];
  size_t obase = (size_t)n * 128 + 2 * lane;
  if (dcnt == 0) {
    *(float2*)(out + obase) = (float2){0.f, 0.f};
    return;
  }
  float m = -1e30f;
  for (int i = lane; i < dcnt; i += 64) m = fmaxf(m, bperm[start + i]);
  #pragma unroll
  for (int s = 32; s; s >>= 1) m = fmaxf(m, __shfl_xor(m, s, 64));

  float acc0 = 0.f, acc1 = 0.f, S = 0.f;
  int cl2 = 2 * lane;
  int i = 0;
  for (; i + 4 <= dcnt; i += 4) {
    unsigned int st[4]; float bb[4];
    #pragma unroll
    for (int j = 0; j < 4; ++j) {
      st[j] = stperm[start + i + j];
      bb[j] = bperm[start + i + j];
    }
    unsigned int av[4], cv[4];
    #pragma unroll
    for (int j = 0; j < 4; ++j) {
      av[j] = *(const unsigned int*)(Abf + ((size_t)(st[j] & 0xFFFFu) << 7) + cl2);
      cv[j] = *(const unsigned int*)(Crelbf + ((st[j] >> 16) << 7) + cl2);
    }
    #pragma unroll
    for (int j = 0; j < 4; ++j) {
      float ex = __expf(bb[j] - m);
      S += ex;
      acc0 = fmaf(ex, bflo(av[j]) + bflo(cv[j]), acc0);
      acc1 = fmaf(ex, bfhi(av[j]) + bfhi(cv[j]), acc1);
    }
  }
  for (; i < dcnt; ++i) {
    unsigned int st = stperm[start + i];
    float ex = __expf(bperm[start + i] - m);
    unsigned int av = *(const unsigned int*)(Abf + ((size_t)(st & 0xFFFFu) << 7) + cl2);
    unsigned int cv = *(const unsigned int*)(Crelbf + ((st >> 16) << 7) + cl2);
    S += ex;
    acc0 = fmaf(ex, bflo(av) + bflo(cv), acc0);
    acc1 = fmaf(ex, bfhi(av) + bfhi(cv), acc1);
  }
  float inv = 1.f / S;
  unsigned int bm = *(const unsigned int*)(Bmbf + obase);
  float o0 = acc0 * inv + bflo(bm);
  float o1 = acc1 * inv + bfhi(bm);
  o0 = o0 > 0.f ? o0 : SLOPE * o0;
  o1 = o1 > 0.f ? o1 : SLOPE * o1;
  *(float2*)(out + obase) = (float2){o0, o1};
}

extern "C" void kernel_launch(void* const* d_in, const int* in_sizes, int n_in,
                              void* d_out, int out_size, void* d_ws, size_t ws_size,
                              hipStream_t stream) {
  const float* x    = (const float*)d_in[0];
  const float* rel  = (const float*)d_in[1];
  const float* W1   = (const float*)d_in[2];
  const float* b1   = (const float*)d_in[3];
  const float* w2   = (const float*)d_in[4];
  const int* edge_index = (const int*)d_in[5];
  const int* edge_type  = (const int*)d_in[6];

  int n_nodes = in_sizes[0] / 128;
  int n_rel   = in_sizes[1] / 128;
  int E       = in_sizes[6];
  const int* srcs = edge_index;
  const int* dsts = edge_index + E;
  float* out = (float*)d_out;

  auto align256 = [](size_t v) { return (v + 255) & ~(size_t)255; };
  char* ws = (char*)d_ws;
  unsigned short* xb     = (unsigned short*)ws; ws += align256((size_t)n_nodes * 128 * 2);
  unsigned short* WT     = (unsigned short*)ws; ws += align256(256 * 128 * 2);
  unsigned short* Abf    = (unsigned short*)ws; ws += align256((size_t)n_nodes * 128 * 2);
  unsigned short* Bmbf   = (unsigned short*)ws; ws += align256((size_t)n_nodes * 128 * 2);
  unsigned short* Crelbf = (unsigned short*)ws; ws += align256((size_t)n_rel * 128 * 2);
  float* pA    = (float*)ws; ws += align256((size_t)n_nodes * 4);
  float* pB    = (float*)ws; ws += align256((size_t)n_nodes * 4);
  float* pC    = (float*)ws; ws += align256((size_t)n_rel * 4);
  int* deg     = (int*)ws;   ws += align256((size_t)n_nodes * 4);
  int* off     = (int*)ws;   ws += align256((size_t)n_nodes * 4);
  int* pos     = (int*)ws;   ws += align256((size_t)n_nodes * 4);
  int* partial = (int*)ws;   ws += align256(1024 * 4);
  unsigned int* stperm = (unsigned int*)ws; ws += align256((size_t)E * 4);
  float* bperm = (float*)ws; ws += align256((size_t)E * 4);

  hipMemsetAsync(deg, 0, (size_t)n_nodes * 4, stream);

  int total8 = n_nodes * 16;
  int B0 = (total8 + 255) / 256;          // conv_x blocks
  int B1 = B0 + 128;                      // conv_w blocks (256*128/256)
  int B2 = B1 + (n_rel + 1) / 2;          // crel blocks (2 rel each)
  int B3 = B2 + (E + 255) / 256;          // hist blocks
  prep<<<B3, 256, 0, stream>>>(x, xb, total8, B0, W1, WT, B1,
                               rel, b1, w2, Crelbf, pC, n_rel, B2,
                               dsts, deg, E);

  gemm_mfma<<<(n_nodes + 63) / 64, 256, 0, stream>>>(
      xb, WT, w2, Abf, Bmbf, pA, pB, n_nodes);

  int nb = (n_nodes + 1023) / 1024;
  scan1<<<nb, 1024, 0, stream>>>(deg, off, partial, n_nodes);
  scan2<<<1, 1024, 0, stream>>>(partial, nb);
  scan3<<<nb, 1024, 0, stream>>>(off, pos, partial, n_nodes);

  fill_perm<<<(E + 255) / 256, 256, 0, stream>>>(
      srcs, dsts, edge_type, pA, pB, pC, pos, stperm, bperm, E);

  aggregate<<<(n_nodes + 3) / 4, 256, 0, stream>>>(
      off, deg, stperm, bperm, Abf, Bmbf, Crelbf, out, n_nodes);
}

// Round 6
// 138.216 us; speedup vs baseline: 1.7623x; 1.0820x over previous
//
#include <hip/hip_runtime.h>
#include <math.h>

#define SLOPE 0.01f

using bf16x8 = __attribute__((ext_vector_type(8))) short;
using f32x4  = __attribute__((ext_vector_type(4))) float;

__device__ __forceinline__ unsigned short f2bf(float f) {
  unsigned int u = __float_as_uint(f);
  unsigned int r = 0x7FFFu + ((u >> 16) & 1u);
  return (unsigned short)((u + r) >> 16);
}
__device__ __forceinline__ float bflo(unsigned int v) {  // low ushort -> float
  return __uint_as_float(v << 16);
}
__device__ __forceinline__ float bfhi(unsigned int v) {  // high ushort -> float
  return __uint_as_float(v & 0xFFFF0000u);
}

// ---------------------------------------------------------------
// prep: fused conv_x | conv_w | crel (2 rel/block) | zero-deg
// (hist moved to its own kernel so deg-zeroing strictly precedes it)
// ---------------------------------------------------------------
__global__ __launch_bounds__(256) void prep(
    const float* __restrict__ x, unsigned short* __restrict__ xb, int total8, int B0,
    const float* __restrict__ W1, unsigned short* __restrict__ WT, int B1,
    const float* __restrict__ rel, const float* __restrict__ b1,
    const float* __restrict__ w2,
    unsigned short* __restrict__ Crelbf, float* __restrict__ pC, int n_rel, int B2,
    int* __restrict__ deg, int n_nodes) {
  int b = blockIdx.x;
  int tid = threadIdx.x;
  if (b < B0) {
    // x fp32 -> bf16, 8 elems/thread
    int i = b * 256 + tid;
    if (i < total8) {
      const float4* p = (const float4*)(x + (size_t)i * 8);
      float4 v0 = p[0], v1 = p[1];
      union { unsigned short us[8]; uint4 u4; } pk;
      pk.us[0] = f2bf(v0.x); pk.us[1] = f2bf(v0.y);
      pk.us[2] = f2bf(v0.z); pk.us[3] = f2bf(v0.w);
      pk.us[4] = f2bf(v1.x); pk.us[5] = f2bf(v1.y);
      pk.us[6] = f2bf(v1.z); pk.us[7] = f2bf(v1.w);
      *(uint4*)(xb + (size_t)i * 8) = pk.u4;
    }
  } else if (b < B1) {
    // WT[n][k] = bf16(W1[(n>=128?128:0)+k][n&127]), 256x128
    int idx = (b - B0) * 256 + tid;   // exactly 32768 over 128 blocks
    int n = idx >> 7, k = idx & 127;
    int src_row = ((n >> 7) << 7) + k;
    WT[n * 128 + k] = f2bf(W1[src_row * 128 + (n & 127)]);
  } else if (b < B2) {
    // Crel[r] = rel[r] @ W1[256:384,:] + b1 (bf16); pC[r] = Crel[r].w2
    __shared__ float rs[2][128];
    __shared__ float red[2][128];
    int h = tid >> 7, d = tid & 127;
    int r = (b - B1) * 2 + h;
    bool valid = r < n_rel;
    rs[h][d] = valid ? rel[r * 128 + d] : 0.f;
    __syncthreads();
    float acc = b1[d];
    for (int k = 0; k < 128; ++k)
      acc = fmaf(rs[h][k], W1[(256 + k) * 128 + d], acc);
    if (valid) Crelbf[r * 128 + d] = f2bf(acc);
    red[h][d] = acc * w2[d];
    __syncthreads();
    for (int s = 64; s > 0; s >>= 1) {
      if (d < s) red[h][d] += red[h][d + s];
      __syncthreads();
    }
    if (d == 0 && valid) pC[r] = red[h][0];
  } else {
    // zero deg (replaces pathological hipMemsetAsync fill, 42us in r5)
    int i = (b - B2) * 256 + tid;
    if (i < n_nodes) deg[i] = 0;
  }
}

__global__ void hist_kernel(const int* __restrict__ dsts, int* __restrict__ deg, int E) {
  int i = blockIdx.x * 256 + threadIdx.x;
  if (i < E) atomicAdd(&deg[dsts[i]], 1);
}

// ---------------------------------------------------------------
// Single-pass MFMA GEMM: [A|B] = xb @ WT^T. Block = 64 M x 256 N,
// 4 waves (2m x 2n), wave = 32M x 128N. A,B stored bf16.
// Fused pA/pB = row-dot with w2 via shfl reduce (no LDS).
// ---------------------------------------------------------------
__global__ __launch_bounds__(256) void gemm_mfma(
    const unsigned short* __restrict__ xb, const unsigned short* __restrict__ WT,
    const float* __restrict__ w2,
    unsigned short* __restrict__ Abf, unsigned short* __restrict__ Bmbf,
    float* __restrict__ pA, float* __restrict__ pB, int M) {
  int tid  = threadIdx.x;
  int wave = tid >> 6, lane = tid & 63;
  int wm = wave >> 1, wn = wave & 1;
  int l15 = lane & 15, l4 = lane >> 4;
  int m0 = blockIdx.x * 64;

  f32x4 acc[2][8];
  #pragma unroll
  for (int mi = 0; mi < 2; ++mi)
    #pragma unroll
    for (int ni = 0; ni < 8; ++ni) acc[mi][ni] = (f32x4){0.f, 0.f, 0.f, 0.f};

  int arow0 = m0 + wm * 32 + l15;
  int arow1 = arow0 + 16;
  int ar0 = arow0 < M ? arow0 : M - 1;
  int ar1 = arow1 < M ? arow1 : M - 1;
  const unsigned short* abase0 = xb + (size_t)ar0 * 128 + l4 * 8;
  const unsigned short* abase1 = xb + (size_t)ar1 * 128 + l4 * 8;
  const unsigned short* bbase  = WT + (size_t)(wn * 128 + l15) * 128 + l4 * 8;

  #pragma unroll
  for (int ks = 0; ks < 4; ++ks) {
    bf16x8 af0 = *(const bf16x8*)(abase0 + ks * 32);
    bf16x8 af1 = *(const bf16x8*)(abase1 + ks * 32);
    #pragma unroll
    for (int ni = 0; ni < 8; ++ni) {
      bf16x8 bf = *(const bf16x8*)(bbase + ni * 16 * 128 + ks * 32);
      acc[0][ni] = __builtin_amdgcn_mfma_f32_16x16x32_bf16(af0, bf, acc[0][ni], 0, 0, 0);
      acc[1][ni] = __builtin_amdgcn_mfma_f32_16x16x32_bf16(af1, bf, acc[1][ni], 0, 0, 0);
    }
  }

  // C/D layout: col = ni*16 + l15, row = m0 + wm*32 + mi*16 + l4*4 + r
  unsigned short* dstp = (wn == 0) ? Abf : Bmbf;
  #pragma unroll
  for (int mi = 0; mi < 2; ++mi) {
    #pragma unroll
    for (int ni = 0; ni < 8; ++ni) {
      int coll = ni * 16 + l15;
      #pragma unroll
      for (int r = 0; r < 4; ++r) {
        int row = m0 + wm * 32 + mi * 16 + l4 * 4 + r;
        if (row < M) dstp[(size_t)row * 128 + coll] = f2bf(acc[mi][ni][r]);
      }
    }
  }

  // fused dot with w2 -> pA (wn==0) / pB (wn==1)
  float w2c[8];
  #pragma unroll
  for (int ni = 0; ni < 8; ++ni) w2c[ni] = w2[ni * 16 + l15];
  float* pdst = (wn == 0) ? pA : pB;
  #pragma unroll
  for (int mi = 0; mi < 2; ++mi) {
    #pragma unroll
    for (int r = 0; r < 4; ++r) {
      float v = 0.f;
      #pragma unroll
      for (int ni = 0; ni < 8; ++ni) v = fmaf(acc[mi][ni][r], w2c[ni], v);
      v += __shfl_xor(v, 1, 64);
      v += __shfl_xor(v, 2, 64);
      v += __shfl_xor(v, 4, 64);
      v += __shfl_xor(v, 8, 64);
      if (l15 == 0) {
        int row = m0 + wm * 32 + mi * 16 + l4 * 4 + r;
        if (row < M) pdst[row] = v;
      }
    }
  }
}

// ---------------------------------------------------------------
// 2-stage scan: scan1 (block-local) + scan3 (wave-prefix of <=64
// partials per block, then add). nb = ceil(n/1024) must be <= 64.
// ---------------------------------------------------------------
__global__ __launch_bounds__(1024) void scan1(
    const int* __restrict__ deg, int* __restrict__ off,
    int* __restrict__ partial, int n) {
  __shared__ int sdata[1024];
  int t = threadIdx.x;
  int i = blockIdx.x * 1024 + t;
  int v = (i < n) ? deg[i] : 0;
  sdata[t] = v;
  __syncthreads();
  for (int s = 1; s < 1024; s <<= 1) {
    int add = (t >= s) ? sdata[t - s] : 0;
    __syncthreads();
    sdata[t] += add;
    __syncthreads();
  }
  if (i < n) off[i] = sdata[t] - v;
  if (t == 1023) partial[blockIdx.x] = sdata[1023];
}

__global__ __launch_bounds__(1024) void scan3(
    int* __restrict__ off, int* __restrict__ pos,
    const int* __restrict__ partial, int n, int nb) {
  __shared__ int carry_s;
  int t = threadIdx.x;
  if (t < 64) {
    int v = (t < nb) ? partial[t] : 0;
    // inclusive wave prefix
    for (int s = 1; s < 64; s <<= 1) {
      int u = __shfl_up(v, s, 64);
      if ((t & 63) >= s) v += u;
    }
    // carry for this block = inclusive prefix at lane blockIdx.x-1
    int b = blockIdx.x;
    int c = __shfl(v, b - 1, 64);
    if (t == 0) carry_s = (b == 0) ? 0 : c;
  }
  __syncthreads();
  int i = blockIdx.x * 1024 + t;
  if (i < n) {
    int o = off[i] + carry_s;
    off[i] = o;
    pos[i] = o;
  }
}

// ---------------------------------------------------------------
// fill CSR slots: ONE packed uint2 {src|type<<16, lrelu-logit bits}
// per edge (single 8B scattered store, halves partial-line writebacks)
// ---------------------------------------------------------------
__global__ void fill_perm(
    const int* __restrict__ srcs, const int* __restrict__ dsts,
    const int* __restrict__ types,
    const float* __restrict__ pA, const float* __restrict__ pB,
    const float* __restrict__ pC,
    int* __restrict__ pos, uint2* __restrict__ stb, int E) {
  int i = blockIdx.x * 256 + threadIdx.x;
  if (i < E) {
    int dn = dsts[i];
    int s  = srcs[i];
    int t  = types[i];
    float bv = pA[s] + pB[dn] + pC[t];
    bv = bv > 0.f ? bv : SLOPE * bv;
    int p = atomicAdd(&pos[dn], 1);
    stb[p] = make_uint2((unsigned int)s | ((unsigned int)t << 16),
                        __float_as_uint(bv));
  }
}

// ---------------------------------------------------------------
// Per-node softmax + weighted gather. 4 edges in flight.
// out[n] = lrelu( sum_e alpha_e (A[s]+Crel[t]) + B[n] ), bf16 gathers
// ---------------------------------------------------------------
__global__ __launch_bounds__(256) void aggregate(
    const int* __restrict__ off, const int* __restrict__ deg,
    const uint2* __restrict__ stb,
    const unsigned short* __restrict__ Abf,
    const unsigned short* __restrict__ Bmbf,
    const unsigned short* __restrict__ Crelbf,
    float* __restrict__ out, int n_nodes) {
  int n = blockIdx.x * 4 + (threadIdx.x >> 6);
  if (n >= n_nodes) return;
  int lane = threadIdx.x & 63;
  int start = off[n];
  int dcnt = deg[n];
  size_t obase = (size_t)n * 128 + 2 * lane;
  if (dcnt == 0) {
    *(float2*)(out + obase) = (float2){0.f, 0.f};
    return;
  }
  float m = -1e30f;
  for (int i = lane; i < dcnt; i += 64)
    m = fmaxf(m, __uint_as_float(stb[start + i].y));
  #pragma unroll
  for (int s = 32; s; s >>= 1) m = fmaxf(m, __shfl_xor(m, s, 64));

  float acc0 = 0.f, acc1 = 0.f, S = 0.f;
  int cl2 = 2 * lane;
  int i = 0;
  for (; i + 4 <= dcnt; i += 4) {
    uint2 e[4];
    #pragma unroll
    for (int j = 0; j < 4; ++j) e[j] = stb[start + i + j];
    unsigned int av[4], cv[4];
    #pragma unroll
    for (int j = 0; j < 4; ++j) {
      av[j] = *(const unsigned int*)(Abf + ((size_t)(e[j].x & 0xFFFFu) << 7) + cl2);
      cv[j] = *(const unsigned int*)(Crelbf + ((e[j].x >> 16) << 7) + cl2);
    }
    #pragma unroll
    for (int j = 0; j < 4; ++j) {
      float ex = __expf(__uint_as_float(e[j].y) - m);
      S += ex;
      acc0 = fmaf(ex, bflo(av[j]) + bflo(cv[j]), acc0);
      acc1 = fmaf(ex, bfhi(av[j]) + bfhi(cv[j]), acc1);
    }
  }
  for (; i < dcnt; ++i) {
    uint2 e = stb[start + i];
    float ex = __expf(__uint_as_float(e.y) - m);
    unsigned int av = *(const unsigned int*)(Abf + ((size_t)(e.x & 0xFFFFu) << 7) + cl2);
    unsigned int cv = *(const unsigned int*)(Crelbf + ((e.x >> 16) << 7) + cl2);
    S += ex;
    acc0 = fmaf(ex, bflo(av) + bflo(cv), acc0);
    acc1 = fmaf(ex, bfhi(av) + bfhi(cv), acc1);
  }
  float inv = 1.f / S;
  unsigned int bm = *(const unsigned int*)(Bmbf + obase);
  float o0 = acc0 * inv + bflo(bm);
  float o1 = acc1 * inv + bfhi(bm);
  o0 = o0 > 0.f ? o0 : SLOPE * o0;
  o1 = o1 > 0.f ? o1 : SLOPE * o1;
  *(float2*)(out + obase) = (float2){o0, o1};
}

extern "C" void kernel_launch(void* const* d_in, const int* in_sizes, int n_in,
                              void* d_out, int out_size, void* d_ws, size_t ws_size,
                              hipStream_t stream) {
  const float* x    = (const float*)d_in[0];
  const float* rel  = (const float*)d_in[1];
  const float* W1   = (const float*)d_in[2];
  const float* b1   = (const float*)d_in[3];
  const float* w2   = (const float*)d_in[4];
  const int* edge_index = (const int*)d_in[5];
  const int* edge_type  = (const int*)d_in[6];

  int n_nodes = in_sizes[0] / 128;
  int n_rel   = in_sizes[1] / 128;
  int E       = in_sizes[6];
  const int* srcs = edge_index;
  const int* dsts = edge_index + E;
  float* out = (float*)d_out;

  auto align256 = [](size_t v) { return (v + 255) & ~(size_t)255; };
  char* ws = (char*)d_ws;
  unsigned short* xb     = (unsigned short*)ws; ws += align256((size_t)n_nodes * 128 * 2);
  unsigned short* WT     = (unsigned short*)ws; ws += align256(256 * 128 * 2);
  unsigned short* Abf    = (unsigned short*)ws; ws += align256((size_t)n_nodes * 128 * 2);
  unsigned short* Bmbf   = (unsigned short*)ws; ws += align256((size_t)n_nodes * 128 * 2);
  unsigned short* Crelbf = (unsigned short*)ws; ws += align256((size_t)n_rel * 128 * 2);
  float* pA    = (float*)ws; ws += align256((size_t)n_nodes * 4);
  float* pB    = (float*)ws; ws += align256((size_t)n_nodes * 4);
  float* pC    = (float*)ws; ws += align256((size_t)n_rel * 4);
  int* deg     = (int*)ws;   ws += align256((size_t)n_nodes * 4);
  int* off     = (int*)ws;   ws += align256((size_t)n_nodes * 4);
  int* pos     = (int*)ws;   ws += align256((size_t)n_nodes * 4);
  int* partial = (int*)ws;   ws += align256(1024 * 4);
  uint2* stb   = (uint2*)ws; ws += align256((size_t)E * 8);

  int total8 = n_nodes * 16;
  int B0 = (total8 + 255) / 256;          // conv_x blocks
  int B1 = B0 + 128;                      // conv_w blocks (256*128/256)
  int B2 = B1 + (n_rel + 1) / 2;          // crel blocks (2 rel each)
  int B3 = B2 + (n_nodes + 255) / 256;    // zero-deg blocks
  prep<<<B3, 256, 0, stream>>>(x, xb, total8, B0, W1, WT, B1,
                               rel, b1, w2, Crelbf, pC, n_rel, B2,
                               deg, n_nodes);

  hist_kernel<<<(E + 255) / 256, 256, 0, stream>>>(dsts, deg, E);

  gemm_mfma<<<(n_nodes + 63) / 64, 256, 0, stream>>>(
      xb, WT, w2, Abf, Bmbf, pA, pB, n_nodes);

  int nb = (n_nodes + 1023) / 1024;       // must be <= 64 (n <= 65536)
  scan1<<<nb, 1024, 0, stream>>>(deg, off, partial, n_nodes);
  scan3<<<nb, 1024, 0, stream>>>(off, pos, partial, n_nodes, nb);

  fill_perm<<<(E + 255) / 256, 256, 0, stream>>>(
      srcs, dsts, edge_type, pA, pB, pC, pos, stb, E);

  aggregate<<<(n_nodes + 3) / 4, 256, 0, stream>>>(
      off, deg, stb, Abf, Bmbf, Crelbf, out, n_nodes);
}

// Round 7
// 137.441 us; speedup vs baseline: 1.7722x; 1.0056x over previous
//
#include <hip/hip_runtime.h>
#include <math.h>

#define SLOPE 0.01f

using bf16x8 = __attribute__((ext_vector_type(8))) short;
using f32x4  = __attribute__((ext_vector_type(4))) float;

__device__ __forceinline__ unsigned short f2bf(float f) {
  unsigned int u = __float_as_uint(f);
  unsigned int r = 0x7FFFu + ((u >> 16) & 1u);
  return (unsigned short)((u + r) >> 16);
}
__device__ __forceinline__ float bflo(unsigned int v) {  // low ushort -> float
  return __uint_as_float(v << 16);
}
__device__ __forceinline__ float bfhi(unsigned int v) {  // high ushort -> float
  return __uint_as_float(v & 0xFFFF0000u);
}

// ---------------------------------------------------------------
// prep: fused conv_x | conv_w | crel (2 rel/block) | zero-deg
// ---------------------------------------------------------------
__global__ __launch_bounds__(256) void prep(
    const float* __restrict__ x, unsigned short* __restrict__ xb, int total8, int B0,
    const float* __restrict__ W1, unsigned short* __restrict__ WT, int B1,
    const float* __restrict__ rel, const float* __restrict__ b1,
    const float* __restrict__ w2,
    unsigned short* __restrict__ Crelbf, float* __restrict__ pC, int n_rel, int B2,
    int* __restrict__ deg, int n_nodes) {
  int b = blockIdx.x;
  int tid = threadIdx.x;
  if (b < B0) {
    // x fp32 -> bf16, 8 elems/thread
    int i = b * 256 + tid;
    if (i < total8) {
      const float4* p = (const float4*)(x + (size_t)i * 8);
      float4 v0 = p[0], v1 = p[1];
      union { unsigned short us[8]; uint4 u4; } pk;
      pk.us[0] = f2bf(v0.x); pk.us[1] = f2bf(v0.y);
      pk.us[2] = f2bf(v0.z); pk.us[3] = f2bf(v0.w);
      pk.us[4] = f2bf(v1.x); pk.us[5] = f2bf(v1.y);
      pk.us[6] = f2bf(v1.z); pk.us[7] = f2bf(v1.w);
      *(uint4*)(xb + (size_t)i * 8) = pk.u4;
    }
  } else if (b < B1) {
    // WT[n][k] = bf16(W1[(n>=128?128:0)+k][n&127]), 256x128
    int idx = (b - B0) * 256 + tid;   // exactly 32768 over 128 blocks
    int n = idx >> 7, k = idx & 127;
    int src_row = ((n >> 7) << 7) + k;
    WT[n * 128 + k] = f2bf(W1[src_row * 128 + (n & 127)]);
  } else if (b < B2) {
    // Crel[r] = rel[r] @ W1[256:384,:] + b1 (bf16); pC[r] = Crel[r].w2
    __shared__ float rs[2][128];
    __shared__ float red[2][128];
    int h = tid >> 7, d = tid & 127;
    int r = (b - B1) * 2 + h;
    bool valid = r < n_rel;
    rs[h][d] = valid ? rel[r * 128 + d] : 0.f;
    __syncthreads();
    float acc = b1[d];
    for (int k = 0; k < 128; ++k)
      acc = fmaf(rs[h][k], W1[(256 + k) * 128 + d], acc);
    if (valid) Crelbf[r * 128 + d] = f2bf(acc);
    red[h][d] = acc * w2[d];
    __syncthreads();
    for (int s = 64; s > 0; s >>= 1) {
      if (d < s) red[h][d] += red[h][d + s];
      __syncthreads();
    }
    if (d == 0 && valid) pC[r] = red[h][0];
  } else {
    // zero deg
    int i = (b - B2) * 256 + tid;
    if (i < n_nodes) deg[i] = 0;
  }
}

__global__ void hist_kernel(const int* __restrict__ dsts, int* __restrict__ deg, int E) {
  int i = blockIdx.x * 256 + threadIdx.x;
  if (i < E) atomicAdd(&deg[dsts[i]], 1);
}

// ---------------------------------------------------------------
// Single-pass MFMA GEMM: [A|B] = xb @ WT^T. Block = 64 M x 256 N,
// 4 waves (2m x 2n), wave = 32M x 128N. A,B stored bf16.
// Fused pA/pB = row-dot with w2 via shfl reduce (no LDS).
// ---------------------------------------------------------------
__global__ __launch_bounds__(256) void gemm_mfma(
    const unsigned short* __restrict__ xb, const unsigned short* __restrict__ WT,
    const float* __restrict__ w2,
    unsigned short* __restrict__ Abf, unsigned short* __restrict__ Bmbf,
    float* __restrict__ pA, float* __restrict__ pB, int M) {
  int tid  = threadIdx.x;
  int wave = tid >> 6, lane = tid & 63;
  int wm = wave >> 1, wn = wave & 1;
  int l15 = lane & 15, l4 = lane >> 4;
  int m0 = blockIdx.x * 64;

  f32x4 acc[2][8];
  #pragma unroll
  for (int mi = 0; mi < 2; ++mi)
    #pragma unroll
    for (int ni = 0; ni < 8; ++ni) acc[mi][ni] = (f32x4){0.f, 0.f, 0.f, 0.f};

  int arow0 = m0 + wm * 32 + l15;
  int arow1 = arow0 + 16;
  int ar0 = arow0 < M ? arow0 : M - 1;
  int ar1 = arow1 < M ? arow1 : M - 1;
  const unsigned short* abase0 = xb + (size_t)ar0 * 128 + l4 * 8;
  const unsigned short* abase1 = xb + (size_t)ar1 * 128 + l4 * 8;
  const unsigned short* bbase  = WT + (size_t)(wn * 128 + l15) * 128 + l4 * 8;

  #pragma unroll
  for (int ks = 0; ks < 4; ++ks) {
    bf16x8 af0 = *(const bf16x8*)(abase0 + ks * 32);
    bf16x8 af1 = *(const bf16x8*)(abase1 + ks * 32);
    #pragma unroll
    for (int ni = 0; ni < 8; ++ni) {
      bf16x8 bf = *(const bf16x8*)(bbase + ni * 16 * 128 + ks * 32);
      acc[0][ni] = __builtin_amdgcn_mfma_f32_16x16x32_bf16(af0, bf, acc[0][ni], 0, 0, 0);
      acc[1][ni] = __builtin_amdgcn_mfma_f32_16x16x32_bf16(af1, bf, acc[1][ni], 0, 0, 0);
    }
  }

  // C/D layout: col = ni*16 + l15, row = m0 + wm*32 + mi*16 + l4*4 + r
  unsigned short* dstp = (wn == 0) ? Abf : Bmbf;
  #pragma unroll
  for (int mi = 0; mi < 2; ++mi) {
    #pragma unroll
    for (int ni = 0; ni < 8; ++ni) {
      int coll = ni * 16 + l15;
      #pragma unroll
      for (int r = 0; r < 4; ++r) {
        int row = m0 + wm * 32 + mi * 16 + l4 * 4 + r;
        if (row < M) dstp[(size_t)row * 128 + coll] = f2bf(acc[mi][ni][r]);
      }
    }
  }

  // fused dot with w2 -> pA (wn==0) / pB (wn==1)
  float w2c[8];
  #pragma unroll
  for (int ni = 0; ni < 8; ++ni) w2c[ni] = w2[ni * 16 + l15];
  float* pdst = (wn == 0) ? pA : pB;
  #pragma unroll
  for (int mi = 0; mi < 2; ++mi) {
    #pragma unroll
    for (int r = 0; r < 4; ++r) {
      float v = 0.f;
      #pragma unroll
      for (int ni = 0; ni < 8; ++ni) v = fmaf(acc[mi][ni][r], w2c[ni], v);
      v += __shfl_xor(v, 1, 64);
      v += __shfl_xor(v, 2, 64);
      v += __shfl_xor(v, 4, 64);
      v += __shfl_xor(v, 8, 64);
      if (l15 == 0) {
        int row = m0 + wm * 32 + mi * 16 + l4 * 4 + r;
        if (row < M) pdst[row] = v;
      }
    }
  }
}

// ---------------------------------------------------------------
// 2-stage scan: scan1 (block-local) + scan3 (wave-prefix of <=64
// partials per block, then add). nb = ceil(n/1024) must be <= 64.
// ---------------------------------------------------------------
__global__ __launch_bounds__(1024) void scan1(
    const int* __restrict__ deg, int* __restrict__ off,
    int* __restrict__ partial, int n) {
  __shared__ int sdata[1024];
  int t = threadIdx.x;
  int i = blockIdx.x * 1024 + t;
  int v = (i < n) ? deg[i] : 0;
  sdata[t] = v;
  __syncthreads();
  for (int s = 1; s < 1024; s <<= 1) {
    int add = (t >= s) ? sdata[t - s] : 0;
    __syncthreads();
    sdata[t] += add;
    __syncthreads();
  }
  if (i < n) off[i] = sdata[t] - v;
  if (t == 1023) partial[blockIdx.x] = sdata[1023];
}

__global__ __launch_bounds__(1024) void scan3(
    int* __restrict__ off, int* __restrict__ pos,
    const int* __restrict__ partial, int n, int nb) {
  __shared__ int carry_s;
  int t = threadIdx.x;
  if (t < 64) {
    int v = (t < nb) ? partial[t] : 0;
    for (int s = 1; s < 64; s <<= 1) {
      int u = __shfl_up(v, s, 64);
      if ((t & 63) >= s) v += u;
    }
    int b = blockIdx.x;
    int c = __shfl(v, b - 1, 64);
    if (t == 0) carry_s = (b == 0) ? 0 : c;
  }
  __syncthreads();
  int i = blockIdx.x * 1024 + t;
  if (i < n) {
    int o = off[i] + carry_s;
    off[i] = o;
    pos[i] = o;
  }
}

// ---------------------------------------------------------------
// fill CSR slots: ONE packed uint (src | type<<16) per edge.
// No logit materialization (softmax computed shift-free in aggregate).
// ---------------------------------------------------------------
__global__ void fill_perm(
    const int* __restrict__ srcs, const int* __restrict__ dsts,
    const int* __restrict__ types,
    int* __restrict__ pos, unsigned int* __restrict__ stperm, int E) {
  int i = blockIdx.x * 256 + threadIdx.x;
  if (i < E) {
    int dn = dsts[i];
    unsigned int st = (unsigned int)srcs[i] | ((unsigned int)types[i] << 16);
    int p = atomicAdd(&pos[dn], 1);
    stperm[p] = st;
  }
}

// ---------------------------------------------------------------
// Single-pass per-node softmax (shift-free: |logit| <~ 3, fp32-safe,
// softmax is shift-invariant so result matches reference) + gather.
// out[n] = lrelu( sum_e alpha_e (A[s]+Crel[t]) + B[n] ), bf16 gathers.
// ---------------------------------------------------------------
__global__ __launch_bounds__(256) void aggregate(
    const int* __restrict__ off, const int* __restrict__ deg,
    const unsigned int* __restrict__ stperm,
    const float* __restrict__ pA, const float* __restrict__ pB,
    const float* __restrict__ pCg,
    const unsigned short* __restrict__ Abf,
    const unsigned short* __restrict__ Bmbf,
    const unsigned short* __restrict__ Crelbf,
    float* __restrict__ out, int n_nodes, int n_rel) {
  __shared__ float pCs[256];
  for (int r = threadIdx.x; r < n_rel; r += 256) pCs[r] = pCg[r];
  __syncthreads();
  int n = blockIdx.x * 4 + (threadIdx.x >> 6);
  if (n >= n_nodes) return;
  int lane = threadIdx.x & 63;
  int start = off[n];
  int dcnt = deg[n];
  size_t obase = (size_t)n * 128 + 2 * lane;
  if (dcnt == 0) {
    *(float2*)(out + obase) = (float2){0.f, 0.f};
    return;
  }
  float pBn = pB[n];
  float acc0 = 0.f, acc1 = 0.f, S = 0.f;
  int cl2 = 2 * lane;
  int i = 0;
  for (; i + 4 <= dcnt; i += 4) {
    unsigned int st[4];
    #pragma unroll
    for (int j = 0; j < 4; ++j) st[j] = stperm[start + i + j];
    unsigned int av[4], cv[4];
    float pa[4];
    #pragma unroll
    for (int j = 0; j < 4; ++j) {
      unsigned int s = st[j] & 0xFFFFu, t = st[j] >> 16;
      av[j] = *(const unsigned int*)(Abf + ((size_t)s << 7) + cl2);
      cv[j] = *(const unsigned int*)(Crelbf + (t << 7) + cl2);
      pa[j] = pA[s];
    }
    #pragma unroll
    for (int j = 0; j < 4; ++j) {
      float b = pa[j] + pBn + pCs[st[j] >> 16];
      b = b > 0.f ? b : SLOPE * b;
      float ex = __expf(b);
      S += ex;
      acc0 = fmaf(ex, bflo(av[j]) + bflo(cv[j]), acc0);
      acc1 = fmaf(ex, bfhi(av[j]) + bfhi(cv[j]), acc1);
    }
  }
  for (; i < dcnt; ++i) {
    unsigned int st = stperm[start + i];
    unsigned int s = st & 0xFFFFu, t = st >> 16;
    unsigned int av = *(const unsigned int*)(Abf + ((size_t)s << 7) + cl2);
    unsigned int cv = *(const unsigned int*)(Crelbf + (t << 7) + cl2);
    float b = pA[s] + pBn + pCs[t];
    b = b > 0.f ? b : SLOPE * b;
    float ex = __expf(b);
    S += ex;
    acc0 = fmaf(ex, bflo(av) + bflo(cv), acc0);
    acc1 = fmaf(ex, bfhi(av) + bfhi(cv), acc1);
  }
  float inv = 1.f / S;
  unsigned int bm = *(const unsigned int*)(Bmbf + obase);
  float o0 = acc0 * inv + bflo(bm);
  float o1 = acc1 * inv + bfhi(bm);
  o0 = o0 > 0.f ? o0 : SLOPE * o0;
  o1 = o1 > 0.f ? o1 : SLOPE * o1;
  *(float2*)(out + obase) = (float2){o0, o1};
}

extern "C" void kernel_launch(void* const* d_in, const int* in_sizes, int n_in,
                              void* d_out, int out_size, void* d_ws, size_t ws_size,
                              hipStream_t stream) {
  const float* x    = (const float*)d_in[0];
  const float* rel  = (const float*)d_in[1];
  const float* W1   = (const float*)d_in[2];
  const float* b1   = (const float*)d_in[3];
  const float* w2   = (const float*)d_in[4];
  const int* edge_index = (const int*)d_in[5];
  const int* edge_type  = (const int*)d_in[6];

  int n_nodes = in_sizes[0] / 128;
  int n_rel   = in_sizes[1] / 128;
  int E       = in_sizes[6];
  const int* srcs = edge_index;
  const int* dsts = edge_index + E;
  float* out = (float*)d_out;

  auto align256 = [](size_t v) { return (v + 255) & ~(size_t)255; };
  char* ws = (char*)d_ws;
  unsigned short* xb     = (unsigned short*)ws; ws += align256((size_t)n_nodes * 128 * 2);
  unsigned short* WT     = (unsigned short*)ws; ws += align256(256 * 128 * 2);
  unsigned short* Abf    = (unsigned short*)ws; ws += align256((size_t)n_nodes * 128 * 2);
  unsigned short* Bmbf   = (unsigned short*)ws; ws += align256((size_t)n_nodes * 128 * 2);
  unsigned short* Crelbf = (unsigned short*)ws; ws += align256((size_t)n_rel * 128 * 2);
  float* pA    = (float*)ws; ws += align256((size_t)n_nodes * 4);
  float* pB    = (float*)ws; ws += align256((size_t)n_nodes * 4);
  float* pC    = (float*)ws; ws += align256((size_t)n_rel * 4);
  int* deg     = (int*)ws;   ws += align256((size_t)n_nodes * 4);
  int* off     = (int*)ws;   ws += align256((size_t)n_nodes * 4);
  int* pos     = (int*)ws;   ws += align256((size_t)n_nodes * 4);
  int* partial = (int*)ws;   ws += align256(1024 * 4);
  unsigned int* stperm = (unsigned int*)ws; ws += align256((size_t)E * 4);

  int total8 = n_nodes * 16;
  int B0 = (total8 + 255) / 256;          // conv_x blocks
  int B1 = B0 + 128;                      // conv_w blocks
  int B2 = B1 + (n_rel + 1) / 2;          // crel blocks (2 rel each)
  int B3 = B2 + (n_nodes + 255) / 256;    // zero-deg blocks
  prep<<<B3, 256, 0, stream>>>(x, xb, total8, B0, W1, WT, B1,
                               rel, b1, w2, Crelbf, pC, n_rel, B2,
                               deg, n_nodes);

  hist_kernel<<<(E + 255) / 256, 256, 0, stream>>>(dsts, deg, E);

  gemm_mfma<<<(n_nodes + 63) / 64, 256, 0, stream>>>(
      xb, WT, w2, Abf, Bmbf, pA, pB, n_nodes);

  int nb = (n_nodes + 1023) / 1024;       // must be <= 64
  scan1<<<nb, 1024, 0, stream>>>(deg, off, partial, n_nodes);
  scan3<<<nb, 1024, 0, stream>>>(off, pos, partial, n_nodes, nb);

  fill_perm<<<(E + 255) / 256, 256, 0, stream>>>(
      srcs, dsts, edge_type, pos, stperm, E);

  aggregate<<<(n_nodes + 3) / 4, 256, 0, stream>>>(
      off, deg, stperm, pA, pB, pC, Abf, Bmbf, Crelbf, out, n_nodes, n_rel);
}

// Round 8
// 130.491 us; speedup vs baseline: 1.8666x; 1.0533x over previous
//
#include <hip/hip_runtime.h>
#include <math.h>

#define SLOPE 0.01f

using bf16x8 = __attribute__((ext_vector_type(8))) short;
using f32x4  = __attribute__((ext_vector_type(4))) float;

__device__ __forceinline__ unsigned short f2bf(float f) {
  unsigned int u = __float_as_uint(f);
  unsigned int r = 0x7FFFu + ((u >> 16) & 1u);
  return (unsigned short)((u + r) >> 16);
}
__device__ __forceinline__ float bflo(unsigned int v) {  // low ushort -> float
  return __uint_as_float(v << 16);
}
__device__ __forceinline__ float bfhi(unsigned int v) {  // high ushort -> float
  return __uint_as_float(v & 0xFFFF0000u);
}
__device__ __forceinline__ bf16x8 pack8(float4 a, float4 b) {
  bf16x8 r;
  r[0] = (short)f2bf(a.x); r[1] = (short)f2bf(a.y);
  r[2] = (short)f2bf(a.z); r[3] = (short)f2bf(a.w);
  r[4] = (short)f2bf(b.x); r[5] = (short)f2bf(b.y);
  r[6] = (short)f2bf(b.z); r[7] = (short)f2bf(b.w);
  return r;
}

// ---------------------------------------------------------------
// prep: fused conv_w | crel (2 rel/block) | zero-deg
// (conv_x removed: GEMM converts x in-register)
// ---------------------------------------------------------------
__global__ __launch_bounds__(256) void prep(
    const float* __restrict__ W1, unsigned short* __restrict__ WT, int B1,
    const float* __restrict__ rel, const float* __restrict__ b1,
    const float* __restrict__ w2,
    unsigned short* __restrict__ Crelbf, float* __restrict__ pC, int n_rel, int B2,
    int* __restrict__ deg, int n_nodes) {
  int b = blockIdx.x;
  int tid = threadIdx.x;
  if (b < B1) {
    // WT[n][k] = bf16(W1[(n>=128?128:0)+k][n&127]), 256x128
    int idx = b * 256 + tid;   // exactly 32768 over 128 blocks
    int n = idx >> 7, k = idx & 127;
    int src_row = ((n >> 7) << 7) + k;
    WT[n * 128 + k] = f2bf(W1[src_row * 128 + (n & 127)]);
  } else if (b < B2) {
    // Crel[r] = rel[r] @ W1[256:384,:] + b1 (bf16); pC[r] = Crel[r].w2
    __shared__ float rs[2][128];
    __shared__ float red[2][128];
    int h = tid >> 7, d = tid & 127;
    int r = (b - B1) * 2 + h;
    bool valid = r < n_rel;
    rs[h][d] = valid ? rel[r * 128 + d] : 0.f;
    __syncthreads();
    float acc = b1[d];
    for (int k = 0; k < 128; ++k)
      acc = fmaf(rs[h][k], W1[(256 + k) * 128 + d], acc);
    if (valid) Crelbf[r * 128 + d] = f2bf(acc);
    red[h][d] = acc * w2[d];
    __syncthreads();
    for (int s = 64; s > 0; s >>= 1) {
      if (d < s) red[h][d] += red[h][d + s];
      __syncthreads();
    }
    if (d == 0 && valid) pC[r] = red[h][0];
  } else {
    // zero deg
    int i = (b - B2) * 256 + tid;
    if (i < n_nodes) deg[i] = 0;
  }
}

// ---------------------------------------------------------------
// GEMM + fused histogram dispatch.
// gemm blocks: [A|B] = bf16(x) @ WT^T, block = 64M x 256N, 4 waves
// (2m x 2n), wave = 32M x 128N. A,B stored bf16; fused pA/pB dot-w2.
// hist blocks (blockIdx >= gblocks): deg histogram atomics.
// Both depend only on prep; hist hides under MFMA.
// ---------------------------------------------------------------
__global__ __launch_bounds__(256) void gemm_hist(
    const float* __restrict__ x, const unsigned short* __restrict__ WT,
    const float* __restrict__ w2,
    unsigned short* __restrict__ Abf, unsigned short* __restrict__ Bmbf,
    float* __restrict__ pA, float* __restrict__ pB, int M, int gblocks,
    const int* __restrict__ dsts, int* __restrict__ deg, int E) {
  if (blockIdx.x >= gblocks) {
    int i = (blockIdx.x - gblocks) * 256 + threadIdx.x;
    if (i < E) atomicAdd(&deg[dsts[i]], 1);
    return;
  }
  int tid  = threadIdx.x;
  int wave = tid >> 6, lane = tid & 63;
  int wm = wave >> 1, wn = wave & 1;
  int l15 = lane & 15, l4 = lane >> 4;
  int m0 = blockIdx.x * 64;

  f32x4 acc[2][8];
  #pragma unroll
  for (int mi = 0; mi < 2; ++mi)
    #pragma unroll
    for (int ni = 0; ni < 8; ++ni) acc[mi][ni] = (f32x4){0.f, 0.f, 0.f, 0.f};

  int arow0 = m0 + wm * 32 + l15;
  int arow1 = arow0 + 16;
  int ar0 = arow0 < M ? arow0 : M - 1;
  int ar1 = arow1 < M ? arow1 : M - 1;
  const float* xbase0 = x + (size_t)ar0 * 128 + l4 * 8;
  const float* xbase1 = x + (size_t)ar1 * 128 + l4 * 8;
  const unsigned short* bbase = WT + (size_t)(wn * 128 + l15) * 128 + l4 * 8;

  #pragma unroll
  for (int ks = 0; ks < 4; ++ks) {
    float4 a0lo = *(const float4*)(xbase0 + ks * 32);
    float4 a0hi = *(const float4*)(xbase0 + ks * 32 + 4);
    float4 a1lo = *(const float4*)(xbase1 + ks * 32);
    float4 a1hi = *(const float4*)(xbase1 + ks * 32 + 4);
    bf16x8 af0 = pack8(a0lo, a0hi);
    bf16x8 af1 = pack8(a1lo, a1hi);
    #pragma unroll
    for (int ni = 0; ni < 8; ++ni) {
      bf16x8 bf = *(const bf16x8*)(bbase + ni * 16 * 128 + ks * 32);
      acc[0][ni] = __builtin_amdgcn_mfma_f32_16x16x32_bf16(af0, bf, acc[0][ni], 0, 0, 0);
      acc[1][ni] = __builtin_amdgcn_mfma_f32_16x16x32_bf16(af1, bf, acc[1][ni], 0, 0, 0);
    }
  }

  // C/D layout: col = ni*16 + l15, row = m0 + wm*32 + mi*16 + l4*4 + r
  unsigned short* dstp = (wn == 0) ? Abf : Bmbf;
  #pragma unroll
  for (int mi = 0; mi < 2; ++mi) {
    #pragma unroll
    for (int ni = 0; ni < 8; ++ni) {
      int coll = ni * 16 + l15;
      #pragma unroll
      for (int r = 0; r < 4; ++r) {
        int row = m0 + wm * 32 + mi * 16 + l4 * 4 + r;
        if (row < M) dstp[(size_t)row * 128 + coll] = f2bf(acc[mi][ni][r]);
      }
    }
  }

  // fused dot with w2 -> pA (wn==0) / pB (wn==1)
  float w2c[8];
  #pragma unroll
  for (int ni = 0; ni < 8; ++ni) w2c[ni] = w2[ni * 16 + l15];
  float* pdst = (wn == 0) ? pA : pB;
  #pragma unroll
  for (int mi = 0; mi < 2; ++mi) {
    #pragma unroll
    for (int r = 0; r < 4; ++r) {
      float v = 0.f;
      #pragma unroll
      for (int ni = 0; ni < 8; ++ni) v = fmaf(acc[mi][ni][r], w2c[ni], v);
      v += __shfl_xor(v, 1, 64);
      v += __shfl_xor(v, 2, 64);
      v += __shfl_xor(v, 4, 64);
      v += __shfl_xor(v, 8, 64);
      if (l15 == 0) {
        int row = m0 + wm * 32 + mi * 16 + l4 * 4 + r;
        if (row < M) pdst[row] = v;
      }
    }
  }
}

// ---------------------------------------------------------------
// 2-stage scan: scan1 (block-local) + scan3 (wave-prefix of <=64
// partials per block, then add). nb = ceil(n/1024) must be <= 64.
// ---------------------------------------------------------------
__global__ __launch_bounds__(1024) void scan1(
    const int* __restrict__ deg, int* __restrict__ off,
    int* __restrict__ partial, int n) {
  __shared__ int sdata[1024];
  int t = threadIdx.x;
  int i = blockIdx.x * 1024 + t;
  int v = (i < n) ? deg[i] : 0;
  sdata[t] = v;
  __syncthreads();
  for (int s = 1; s < 1024; s <<= 1) {
    int add = (t >= s) ? sdata[t - s] : 0;
    __syncthreads();
    sdata[t] += add;
    __syncthreads();
  }
  if (i < n) off[i] = sdata[t] - v;
  if (t == 1023) partial[blockIdx.x] = sdata[1023];
}

__global__ __launch_bounds__(1024) void scan3(
    int* __restrict__ off, int* __restrict__ pos,
    const int* __restrict__ partial, int n, int nb) {
  __shared__ int carry_s;
  int t = threadIdx.x;
  if (t < 64) {
    int v = (t < nb) ? partial[t] : 0;
    for (int s = 1; s < 64; s <<= 1) {
      int u = __shfl_up(v, s, 64);
      if ((t & 63) >= s) v += u;
    }
    int b = blockIdx.x;
    int c = __shfl(v, b - 1, 64);
    if (t == 0) carry_s = (b == 0) ? 0 : c;
  }
  __syncthreads();
  int i = blockIdx.x * 1024 + t;
  if (i < n) {
    int o = off[i] + carry_s;
    off[i] = o;
    pos[i] = o;
  }
}

// ---------------------------------------------------------------
// fill CSR slots: ONE packed uint (src | type<<16) per edge.
// ---------------------------------------------------------------
__global__ void fill_perm(
    const int* __restrict__ srcs, const int* __restrict__ dsts,
    const int* __restrict__ types,
    int* __restrict__ pos, unsigned int* __restrict__ stperm, int E) {
  int i = blockIdx.x * 256 + threadIdx.x;
  if (i < E) {
    int dn = dsts[i];
    unsigned int st = (unsigned int)srcs[i] | ((unsigned int)types[i] << 16);
    int p = atomicAdd(&pos[dn], 1);
    stperm[p] = st;
  }
}

// ---------------------------------------------------------------
// Single-pass per-node softmax (shift-free: |logit| <~ 3, fp32-safe,
// softmax is shift-invariant so result matches reference) + gather.
// out[n] = lrelu( sum_e alpha_e (A[s]+Crel[t]) + B[n] ), bf16 gathers.
// ---------------------------------------------------------------
__global__ __launch_bounds__(256) void aggregate(
    const int* __restrict__ off, const int* __restrict__ deg,
    const unsigned int* __restrict__ stperm,
    const float* __restrict__ pA, const float* __restrict__ pB,
    const float* __restrict__ pCg,
    const unsigned short* __restrict__ Abf,
    const unsigned short* __restrict__ Bmbf,
    const unsigned short* __restrict__ Crelbf,
    float* __restrict__ out, int n_nodes, int n_rel) {
  __shared__ float pCs[256];
  for (int r = threadIdx.x; r < n_rel; r += 256) pCs[r] = pCg[r];
  __syncthreads();
  int n = blockIdx.x * 4 + (threadIdx.x >> 6);
  if (n >= n_nodes) return;
  int lane = threadIdx.x & 63;
  int start = off[n];
  int dcnt = deg[n];
  size_t obase = (size_t)n * 128 + 2 * lane;
  if (dcnt == 0) {
    *(float2*)(out + obase) = (float2){0.f, 0.f};
    return;
  }
  float pBn = pB[n];
  float acc0 = 0.f, acc1 = 0.f, S = 0.f;
  int cl2 = 2 * lane;
  int i = 0;
  for (; i + 4 <= dcnt; i += 4) {
    unsigned int st[4];
    #pragma unroll
    for (int j = 0; j < 4; ++j) st[j] = stperm[start + i + j];
    unsigned int av[4], cv[4];
    float pa[4];
    #pragma unroll
    for (int j = 0; j < 4; ++j) {
      unsigned int s = st[j] & 0xFFFFu, t = st[j] >> 16;
      av[j] = *(const unsigned int*)(Abf + ((size_t)s << 7) + cl2);
      cv[j] = *(const unsigned int*)(Crelbf + (t << 7) + cl2);
      pa[j] = pA[s];
    }
    #pragma unroll
    for (int j = 0; j < 4; ++j) {
      float b = pa[j] + pBn + pCs[st[j] >> 16];
      b = b > 0.f ? b : SLOPE * b;
      float ex = __expf(b);
      S += ex;
      acc0 = fmaf(ex, bflo(av[j]) + bflo(cv[j]), acc0);
      acc1 = fmaf(ex, bfhi(av[j]) + bfhi(cv[j]), acc1);
    }
  }
  for (; i < dcnt; ++i) {
    unsigned int st = stperm[start + i];
    unsigned int s = st & 0xFFFFu, t = st >> 16;
    unsigned int av = *(const unsigned int*)(Abf + ((size_t)s << 7) + cl2);
    unsigned int cv = *(const unsigned int*)(Crelbf + (t << 7) + cl2);
    float b = pA[s] + pBn + pCs[t];
    b = b > 0.f ? b : SLOPE * b;
    float ex = __expf(b);
    S += ex;
    acc0 = fmaf(ex, bflo(av) + bflo(cv), acc0);
    acc1 = fmaf(ex, bfhi(av) + bfhi(cv), acc1);
  }
  float inv = 1.f / S;
  unsigned int bm = *(const unsigned int*)(Bmbf + obase);
  float o0 = acc0 * inv + bflo(bm);
  float o1 = acc1 * inv + bfhi(bm);
  o0 = o0 > 0.f ? o0 : SLOPE * o0;
  o1 = o1 > 0.f ? o1 : SLOPE * o1;
  *(float2*)(out + obase) = (float2){o0, o1};
}

extern "C" void kernel_launch(void* const* d_in, const int* in_sizes, int n_in,
                              void* d_out, int out_size, void* d_ws, size_t ws_size,
                              hipStream_t stream) {
  const float* x    = (const float*)d_in[0];
  const float* rel  = (const float*)d_in[1];
  const float* W1   = (const float*)d_in[2];
  const float* b1   = (const float*)d_in[3];
  const float* w2   = (const float*)d_in[4];
  const int* edge_index = (const int*)d_in[5];
  const int* edge_type  = (const int*)d_in[6];

  int n_nodes = in_sizes[0] / 128;
  int n_rel   = in_sizes[1] / 128;
  int E       = in_sizes[6];
  const int* srcs = edge_index;
  const int* dsts = edge_index + E;
  float* out = (float*)d_out;

  auto align256 = [](size_t v) { return (v + 255) & ~(size_t)255; };
  char* ws = (char*)d_ws;
  unsigned short* WT     = (unsigned short*)ws; ws += align256(256 * 128 * 2);
  unsigned short* Abf    = (unsigned short*)ws; ws += align256((size_t)n_nodes * 128 * 2);
  unsigned short* Bmbf   = (unsigned short*)ws; ws += align256((size_t)n_nodes * 128 * 2);
  unsigned short* Crelbf = (unsigned short*)ws; ws += align256((size_t)n_rel * 128 * 2);
  float* pA    = (float*)ws; ws += align256((size_t)n_nodes * 4);
  float* pB    = (float*)ws; ws += align256((size_t)n_nodes * 4);
  float* pC    = (float*)ws; ws += align256((size_t)n_rel * 4);
  int* deg     = (int*)ws;   ws += align256((size_t)n_nodes * 4);
  int* off     = (int*)ws;   ws += align256((size_t)n_nodes * 4);
  int* pos     = (int*)ws;   ws += align256((size_t)n_nodes * 4);
  int* partial = (int*)ws;   ws += align256(1024 * 4);
  unsigned int* stperm = (unsigned int*)ws; ws += align256((size_t)E * 4);

  int B1 = 128;                           // conv_w blocks
  int B2 = B1 + (n_rel + 1) / 2;          // crel blocks (2 rel each)
  int B3 = B2 + (n_nodes + 255) / 256;    // zero-deg blocks
  prep<<<B3, 256, 0, stream>>>(W1, WT, B1, rel, b1, w2, Crelbf, pC, n_rel, B2,
                               deg, n_nodes);

  int gblocks = (n_nodes + 63) / 64;
  int hblocks = (E + 255) / 256;
  gemm_hist<<<gblocks + hblocks, 256, 0, stream>>>(
      x, WT, w2, Abf, Bmbf, pA, pB, n_nodes, gblocks, dsts, deg, E);

  int nb = (n_nodes + 1023) / 1024;       // must be <= 64
  scan1<<<nb, 1024, 0, stream>>>(deg, off, partial, n_nodes);
  scan3<<<nb, 1024, 0, stream>>>(off, pos, partial, n_nodes, nb);

  fill_perm<<<(E + 255) / 256, 256, 0, stream>>>(
      srcs, dsts, edge_type, pos, stperm, E);

  aggregate<<<(n_nodes + 3) / 4, 256, 0, stream>>>(
      off, deg, stperm, pA, pB, pC, Abf, Bmbf, Crelbf, out, n_nodes, n_rel);
}

// Round 9
// 116.851 us; speedup vs baseline: 2.0845x; 1.1167x over previous
//
#include <hip/hip_runtime.h>
#include <math.h>

#define SLOPE 0.01f

using bf16x8 = __attribute__((ext_vector_type(8))) short;
using f32x4  = __attribute__((ext_vector_type(4))) float;

__device__ __forceinline__ unsigned short f2bf(float f) {
  unsigned int u = __float_as_uint(f);
  unsigned int r = 0x7FFFu + ((u >> 16) & 1u);
  return (unsigned short)((u + r) >> 16);
}
__device__ __forceinline__ float bflo(unsigned int v) {  // low ushort -> float
  return __uint_as_float(v << 16);
}
__device__ __forceinline__ float bfhi(unsigned int v) {  // high ushort -> float
  return __uint_as_float(v & 0xFFFF0000u);
}
__device__ __forceinline__ bf16x8 pack8(float4 a, float4 b) {
  bf16x8 r;
  r[0] = (short)f2bf(a.x); r[1] = (short)f2bf(a.y);
  r[2] = (short)f2bf(a.z); r[3] = (short)f2bf(a.w);
  r[4] = (short)f2bf(b.x); r[5] = (short)f2bf(b.y);
  r[6] = (short)f2bf(b.z); r[7] = (short)f2bf(b.w);
  return r;
}

// ---------------------------------------------------------------
// prep: fused conv_w | crel (2 rel/block) | zero-deg
// ---------------------------------------------------------------
__global__ __launch_bounds__(256) void prep(
    const float* __restrict__ W1, unsigned short* __restrict__ WT, int B1,
    const float* __restrict__ rel, const float* __restrict__ b1,
    const float* __restrict__ w2,
    unsigned short* __restrict__ Crelbf, float* __restrict__ pC, int n_rel, int B2,
    int* __restrict__ deg, int n_nodes) {
  int b = blockIdx.x;
  int tid = threadIdx.x;
  if (b < B1) {
    // WT[n][k] = bf16(W1[(n>=128?128:0)+k][n&127]), 256x128
    int idx = b * 256 + tid;   // exactly 32768 over 128 blocks
    int n = idx >> 7, k = idx & 127;
    int src_row = ((n >> 7) << 7) + k;
    WT[n * 128 + k] = f2bf(W1[src_row * 128 + (n & 127)]);
  } else if (b < B2) {
    // Crel[r] = rel[r] @ W1[256:384,:] + b1 (bf16); pC[r] = Crel[r].w2
    __shared__ float rs[2][128];
    __shared__ float red[2][128];
    int h = tid >> 7, d = tid & 127;
    int r = (b - B1) * 2 + h;
    bool valid = r < n_rel;
    rs[h][d] = valid ? rel[r * 128 + d] : 0.f;
    __syncthreads();
    float acc = b1[d];
    for (int k = 0; k < 128; ++k)
      acc = fmaf(rs[h][k], W1[(256 + k) * 128 + d], acc);
    if (valid) Crelbf[r * 128 + d] = f2bf(acc);
    red[h][d] = acc * w2[d];
    __syncthreads();
    for (int s = 64; s > 0; s >>= 1) {
      if (d < s) red[h][d] += red[h][d + s];
      __syncthreads();
    }
    if (d == 0 && valid) pC[r] = red[h][0];
  } else {
    // zero deg
    int i = (b - B2) * 256 + tid;
    if (i < n_nodes) deg[i] = 0;
  }
}

// ---------------------------------------------------------------
// GEMM + fused histogram (with rank recording).
// gemm blocks: [A|B] = bf16(x) @ WT^T, block = 64M x 256N, 4 waves
// (2m x 2n), wave = 32M x 128N. A,B stored bf16; fused pA/pB dot-w2.
// hist blocks: rank[e] = old count of deg[dst[e]] (the ONLY atomic
// pass over edges; fill_perm becomes atomic-free).
// ---------------------------------------------------------------
__global__ __launch_bounds__(256) void gemm_hist(
    const float* __restrict__ x, const unsigned short* __restrict__ WT,
    const float* __restrict__ w2,
    unsigned short* __restrict__ Abf, unsigned short* __restrict__ Bmbf,
    float* __restrict__ pA, float* __restrict__ pB, int M, int gblocks,
    const int* __restrict__ dsts, int* __restrict__ deg,
    int* __restrict__ rank, int E) {
  if (blockIdx.x >= gblocks) {
    int i = (blockIdx.x - gblocks) * 256 + threadIdx.x;
    if (i < E) rank[i] = atomicAdd(&deg[dsts[i]], 1);
    return;
  }
  int tid  = threadIdx.x;
  int wave = tid >> 6, lane = tid & 63;
  int wm = wave >> 1, wn = wave & 1;
  int l15 = lane & 15, l4 = lane >> 4;
  int m0 = blockIdx.x * 64;

  f32x4 acc[2][8];
  #pragma unroll
  for (int mi = 0; mi < 2; ++mi)
    #pragma unroll
    for (int ni = 0; ni < 8; ++ni) acc[mi][ni] = (f32x4){0.f, 0.f, 0.f, 0.f};

  int arow0 = m0 + wm * 32 + l15;
  int arow1 = arow0 + 16;
  int ar0 = arow0 < M ? arow0 : M - 1;
  int ar1 = arow1 < M ? arow1 : M - 1;
  const float* xbase0 = x + (size_t)ar0 * 128 + l4 * 8;
  const float* xbase1 = x + (size_t)ar1 * 128 + l4 * 8;
  const unsigned short* bbase = WT + (size_t)(wn * 128 + l15) * 128 + l4 * 8;

  #pragma unroll
  for (int ks = 0; ks < 4; ++ks) {
    float4 a0lo = *(const float4*)(xbase0 + ks * 32);
    float4 a0hi = *(const float4*)(xbase0 + ks * 32 + 4);
    float4 a1lo = *(const float4*)(xbase1 + ks * 32);
    float4 a1hi = *(const float4*)(xbase1 + ks * 32 + 4);
    bf16x8 af0 = pack8(a0lo, a0hi);
    bf16x8 af1 = pack8(a1lo, a1hi);
    #pragma unroll
    for (int ni = 0; ni < 8; ++ni) {
      bf16x8 bf = *(const bf16x8*)(bbase + ni * 16 * 128 + ks * 32);
      acc[0][ni] = __builtin_amdgcn_mfma_f32_16x16x32_bf16(af0, bf, acc[0][ni], 0, 0, 0);
      acc[1][ni] = __builtin_amdgcn_mfma_f32_16x16x32_bf16(af1, bf, acc[1][ni], 0, 0, 0);
    }
  }

  // C/D layout: col = ni*16 + l15, row = m0 + wm*32 + mi*16 + l4*4 + r
  unsigned short* dstp = (wn == 0) ? Abf : Bmbf;
  #pragma unroll
  for (int mi = 0; mi < 2; ++mi) {
    #pragma unroll
    for (int ni = 0; ni < 8; ++ni) {
      int coll = ni * 16 + l15;
      #pragma unroll
      for (int r = 0; r < 4; ++r) {
        int row = m0 + wm * 32 + mi * 16 + l4 * 4 + r;
        if (row < M) dstp[(size_t)row * 128 + coll] = f2bf(acc[mi][ni][r]);
      }
    }
  }

  // fused dot with w2 -> pA (wn==0) / pB (wn==1)
  float w2c[8];
  #pragma unroll
  for (int ni = 0; ni < 8; ++ni) w2c[ni] = w2[ni * 16 + l15];
  float* pdst = (wn == 0) ? pA : pB;
  #pragma unroll
  for (int mi = 0; mi < 2; ++mi) {
    #pragma unroll
    for (int r = 0; r < 4; ++r) {
      float v = 0.f;
      #pragma unroll
      for (int ni = 0; ni < 8; ++ni) v = fmaf(acc[mi][ni][r], w2c[ni], v);
      v += __shfl_xor(v, 1, 64);
      v += __shfl_xor(v, 2, 64);
      v += __shfl_xor(v, 4, 64);
      v += __shfl_xor(v, 8, 64);
      if (l15 == 0) {
        int row = m0 + wm * 32 + mi * 16 + l4 * 4 + r;
        if (row < M) pdst[row] = v;
      }
    }
  }
}

// ---------------------------------------------------------------
// 2-stage scan: scan1 (block-local) + scan3 (wave-prefix of <=64
// partials per block, then add). nb = ceil(n/1024) must be <= 64.
// ---------------------------------------------------------------
__global__ __launch_bounds__(1024) void scan1(
    const int* __restrict__ deg, int* __restrict__ off,
    int* __restrict__ partial, int n) {
  __shared__ int sdata[1024];
  int t = threadIdx.x;
  int i = blockIdx.x * 1024 + t;
  int v = (i < n) ? deg[i] : 0;
  sdata[t] = v;
  __syncthreads();
  for (int s = 1; s < 1024; s <<= 1) {
    int add = (t >= s) ? sdata[t - s] : 0;
    __syncthreads();
    sdata[t] += add;
    __syncthreads();
  }
  if (i < n) off[i] = sdata[t] - v;
  if (t == 1023) partial[blockIdx.x] = sdata[1023];
}

__global__ __launch_bounds__(1024) void scan3(
    int* __restrict__ off, const int* __restrict__ partial, int n, int nb) {
  __shared__ int carry_s;
  int t = threadIdx.x;
  if (t < 64) {
    int v = (t < nb) ? partial[t] : 0;
    for (int s = 1; s < 64; s <<= 1) {
      int u = __shfl_up(v, s, 64);
      if ((t & 63) >= s) v += u;
    }
    int b = blockIdx.x;
    int c = __shfl(v, b - 1, 64);
    if (t == 0) carry_s = (b == 0) ? 0 : c;
  }
  __syncthreads();
  int i = blockIdx.x * 1024 + t;
  if (i < n) off[i] += carry_s;
}

// ---------------------------------------------------------------
// fill CSR slots, ATOMIC-FREE: slot = off[dst] + rank[e].
// One packed uint (src | type<<16) per edge.
// ---------------------------------------------------------------
__global__ void fill_perm(
    const int* __restrict__ srcs, const int* __restrict__ dsts,
    const int* __restrict__ types, const int* __restrict__ rank,
    const int* __restrict__ off, unsigned int* __restrict__ stperm, int E) {
  int i = blockIdx.x * 256 + threadIdx.x;
  if (i < E) {
    int p = off[dsts[i]] + rank[i];
    stperm[p] = (unsigned int)srcs[i] | ((unsigned int)types[i] << 16);
  }
}

// ---------------------------------------------------------------
// Single-pass per-node softmax (shift-free: |logit| <~ 3, fp32-safe,
// softmax is shift-invariant so result matches reference) + gather.
// out[n] = lrelu( sum_e alpha_e (A[s]+Crel[t]) + B[n] ), bf16 gathers.
// ---------------------------------------------------------------
__global__ __launch_bounds__(256) void aggregate(
    const int* __restrict__ off, const int* __restrict__ deg,
    const unsigned int* __restrict__ stperm,
    const float* __restrict__ pA, const float* __restrict__ pB,
    const float* __restrict__ pCg,
    const unsigned short* __restrict__ Abf,
    const unsigned short* __restrict__ Bmbf,
    const unsigned short* __restrict__ Crelbf,
    float* __restrict__ out, int n_nodes, int n_rel) {
  __shared__ float pCs[256];
  for (int r = threadIdx.x; r < n_rel; r += 256) pCs[r] = pCg[r];
  __syncthreads();
  int n = blockIdx.x * 4 + (threadIdx.x >> 6);
  if (n >= n_nodes) return;
  int lane = threadIdx.x & 63;
  int start = off[n];
  int dcnt = deg[n];
  size_t obase = (size_t)n * 128 + 2 * lane;
  if (dcnt == 0) {
    *(float2*)(out + obase) = (float2){0.f, 0.f};
    return;
  }
  float pBn = pB[n];
  float acc0 = 0.f, acc1 = 0.f, S = 0.f;
  int cl2 = 2 * lane;
  int i = 0;
  for (; i + 4 <= dcnt; i += 4) {
    unsigned int st[4];
    #pragma unroll
    for (int j = 0; j < 4; ++j) st[j] = stperm[start + i + j];
    unsigned int av[4], cv[4];
    float pa[4];
    #pragma unroll
    for (int j = 0; j < 4; ++j) {
      unsigned int s = st[j] & 0xFFFFu, t = st[j] >> 16;
      av[j] = *(const unsigned int*)(Abf + ((size_t)s << 7) + cl2);
      cv[j] = *(const unsigned int*)(Crelbf + (t << 7) + cl2);
      pa[j] = pA[s];
    }
    #pragma unroll
    for (int j = 0; j < 4; ++j) {
      float b = pa[j] + pBn + pCs[st[j] >> 16];
      b = b > 0.f ? b : SLOPE * b;
      float ex = __expf(b);
      S += ex;
      acc0 = fmaf(ex, bflo(av[j]) + bflo(cv[j]), acc0);
      acc1 = fmaf(ex, bfhi(av[j]) + bfhi(cv[j]), acc1);
    }
  }
  for (; i < dcnt; ++i) {
    unsigned int st = stperm[start + i];
    unsigned int s = st & 0xFFFFu, t = st >> 16;
    unsigned int av = *(const unsigned int*)(Abf + ((size_t)s << 7) + cl2);
    unsigned int cv = *(const unsigned int*)(Crelbf + (t << 7) + cl2);
    float b = pA[s] + pBn + pCs[t];
    b = b > 0.f ? b : SLOPE * b;
    float ex = __expf(b);
    S += ex;
    acc0 = fmaf(ex, bflo(av) + bflo(cv), acc0);
    acc1 = fmaf(ex, bfhi(av) + bfhi(cv), acc1);
  }
  float inv = 1.f / S;
  unsigned int bm = *(const unsigned int*)(Bmbf + obase);
  float o0 = acc0 * inv + bflo(bm);
  float o1 = acc1 * inv + bfhi(bm);
  o0 = o0 > 0.f ? o0 : SLOPE * o0;
  o1 = o1 > 0.f ? o1 : SLOPE * o1;
  *(float2*)(out + obase) = (float2){o0, o1};
}

extern "C" void kernel_launch(void* const* d_in, const int* in_sizes, int n_in,
                              void* d_out, int out_size, void* d_ws, size_t ws_size,
                              hipStream_t stream) {
  const float* x    = (const float*)d_in[0];
  const float* rel  = (const float*)d_in[1];
  const float* W1   = (const float*)d_in[2];
  const float* b1   = (const float*)d_in[3];
  const float* w2   = (const float*)d_in[4];
  const int* edge_index = (const int*)d_in[5];
  const int* edge_type  = (const int*)d_in[6];

  int n_nodes = in_sizes[0] / 128;
  int n_rel   = in_sizes[1] / 128;
  int E       = in_sizes[6];
  const int* srcs = edge_index;
  const int* dsts = edge_index + E;
  float* out = (float*)d_out;

  auto align256 = [](size_t v) { return (v + 255) & ~(size_t)255; };
  char* ws = (char*)d_ws;
  unsigned short* WT     = (unsigned short*)ws; ws += align256(256 * 128 * 2);
  unsigned short* Abf    = (unsigned short*)ws; ws += align256((size_t)n_nodes * 128 * 2);
  unsigned short* Bmbf   = (unsigned short*)ws; ws += align256((size_t)n_nodes * 128 * 2);
  unsigned short* Crelbf = (unsigned short*)ws; ws += align256((size_t)n_rel * 128 * 2);
  float* pA    = (float*)ws; ws += align256((size_t)n_nodes * 4);
  float* pB    = (float*)ws; ws += align256((size_t)n_nodes * 4);
  float* pC    = (float*)ws; ws += align256((size_t)n_rel * 4);
  int* deg     = (int*)ws;   ws += align256((size_t)n_nodes * 4);
  int* off     = (int*)ws;   ws += align256((size_t)n_nodes * 4);
  int* rank    = (int*)ws;   ws += align256((size_t)E * 4);
  int* partial = (int*)ws;   ws += align256(1024 * 4);
  unsigned int* stperm = (unsigned int*)ws; ws += align256((size_t)E * 4);

  int B1 = 128;                           // conv_w blocks
  int B2 = B1 + (n_rel + 1) / 2;          // crel blocks (2 rel each)
  int B3 = B2 + (n_nodes + 255) / 256;    // zero-deg blocks
  prep<<<B3, 256, 0, stream>>>(W1, WT, B1, rel, b1, w2, Crelbf, pC, n_rel, B2,
                               deg, n_nodes);

  int gblocks = (n_nodes + 63) / 64;
  int hblocks = (E + 255) / 256;
  gemm_hist<<<gblocks + hblocks, 256, 0, stream>>>(
      x, WT, w2, Abf, Bmbf, pA, pB, n_nodes, gblocks, dsts, deg, rank, E);

  int nb = (n_nodes + 1023) / 1024;       // must be <= 64
  scan1<<<nb, 1024, 0, stream>>>(deg, off, partial, n_nodes);
  scan3<<<nb, 1024, 0, stream>>>(off, partial, n_nodes, nb);

  fill_perm<<<(E + 255) / 256, 256, 0, stream>>>(
      srcs, dsts, edge_type, rank, off, stperm, E);

  aggregate<<<(n_nodes + 3) / 4, 256, 0, stream>>>(
      off, deg, stperm, pA, pB, pC, Abf, Bmbf, Crelbf, out, n_nodes, n_rel);
}